// Round 3
// baseline (234.462 us; speedup 1.0000x reference)
//
#include <hip/hip_runtime.h>
#include <hip/hip_bf16.h>
#include <math.h>

// Problem constants
#define BB 4
#define LL 512
#define DD 768
#define HH 12
#define DH 64
#define RR 128
#define BL (BB*LL)      // 2048
#define D3 (3*DD)       // 2304
#define NC 8            // chunks over L
#define CT 64           // chunk length
#define PI_F 3.14159265358979323846f

typedef short bf16x8 __attribute__((ext_vector_type(8)));
typedef float f32x4 __attribute__((ext_vector_type(4)));

__device__ __forceinline__ float sigmoidf_(float x) { return 1.0f / (1.0f + expf(-x)); }
__device__ __forceinline__ float elu1f_(float x)    { return x > 0.0f ? x + 1.0f : expf(x); }
__device__ __forceinline__ unsigned short f2bf(float f) {
    unsigned u = __float_as_uint(f);
    unsigned r = u + 0x7FFF + ((u >> 16) & 1);
    return (unsigned short)(r >> 16);
}
__device__ __forceinline__ int packbf2(float lo, float hi) {
    return (int)f2bf(lo) | ((int)f2bf(hi) << 16);
}
// async global->LDS DMA, 16 B per lane; LDS dst = wave-uniform base + lane*16
__device__ __forceinline__ void gll16(const void* g, void* l) {
    __builtin_amdgcn_global_load_lds(
        (const __attribute__((address_space(1))) void*)g,
        (__attribute__((address_space(3))) void*)l, 16, 0, 0);
}

// ---------------------------------------------------------------------------
// Kernel 1: row layernorm over D=768 (x -> x_norm bf16) + raw x -> bf16
// ---------------------------------------------------------------------------
__global__ __launch_bounds__(256) void ln_row_kernel(const float* __restrict__ x,
                                                     const float* __restrict__ g,
                                                     const float* __restrict__ b,
                                                     unsigned short* __restrict__ xn,
                                                     unsigned short* __restrict__ xb) {
    int row = blockIdx.x;
    int t = threadIdx.x;
    int w = t >> 6;
    int lane = t & 63;
    float v[3];
    float s = 0.f, s2 = 0.f;
#pragma unroll
    for (int i = 0; i < 3; i++) {
        v[i] = x[(size_t)row * DD + t + i * 256];
        s += v[i];
        s2 += v[i] * v[i];
    }
#pragma unroll
    for (int off = 1; off < 64; off <<= 1) {
        s  += __shfl_xor(s, off);
        s2 += __shfl_xor(s2, off);
    }
    __shared__ float rs[4], rs2[4];
    if (lane == 0) { rs[w] = s; rs2[w] = s2; }
    __syncthreads();
    s  = rs[0] + rs[1] + rs[2] + rs[3];
    s2 = rs2[0] + rs2[1] + rs2[2] + rs2[3];
    float mu = s * (1.0f / DD);
    float var = s2 * (1.0f / DD) - mu * mu;
    float rstd = rsqrtf(var + 1e-5f);
#pragma unroll
    for (int i = 0; i < 3; i++) {
        int col = t + i * 256;
        xn[(size_t)row * DD + col] = f2bf((v[i] - mu) * rstd * g[col] + b[col]);
        xb[(size_t)row * DD + col] = f2bf(v[i]);
    }
}

// ---------------------------------------------------------------------------
// Kernel 1c: all three weight transposes f32 [K][N] -> bf16 [N][K] in one launch
// ---------------------------------------------------------------------------
__global__ __launch_bounds__(256) void transpose_all_kernel(const float* __restrict__ Wqkv,
                                                            const float* __restrict__ Wb1,
                                                            const float* __restrict__ Wproj,
                                                            unsigned short* __restrict__ wqkvt,
                                                            unsigned short* __restrict__ wb1t,
                                                            unsigned short* __restrict__ wprojt) {
    __shared__ float tile[32][33];
    int bid = blockIdx.x;
    const float* in; unsigned short* out; int K, N, bx, by;
    if (bid < 1728)      { in = Wqkv;  out = wqkvt;  K = DD; N = D3; bx = bid % 72; by = bid / 72; }
    else if (bid < 1824) { bid -= 1728; in = Wb1;  out = wb1t;  K = DD; N = RR; bx = bid % 4;  by = bid / 4; }
    else                 { bid -= 1824; in = Wproj; out = wprojt; K = DD; N = DD; bx = bid % 24; by = bid / 24; }
    int n0 = bx * 32, k0 = by * 32;
    int tx = threadIdx.x & 31, ty = threadIdx.x >> 5;   // ty 0..7
#pragma unroll
    for (int i = 0; i < 4; i++)
        tile[ty + i * 8][tx] = in[(size_t)(k0 + ty + i * 8) * N + n0 + tx];
    __syncthreads();
#pragma unroll
    for (int i = 0; i < 4; i++)
        out[(size_t)(n0 + ty + i * 8) * K + k0 + tx] = f2bf(tile[tx][ty + i * 8]);
}

// ---------------------------------------------------------------------------
// Kernel 2: bf16 MFMA GEMM, m97 structure: global_load_lds(16B) staging into
// XOR-swizzled unpadded LDS; 128x128 tile, BK=32, 4 waves 2x2, 4x4 of 16x16x32.
// A: bf16 [M][K]; Bt: bf16 [N][K]; C fp32 (+bias | silu).
// swz(r) = (r&3)^((r>>2)&3) applied to 16B column groups -> 2-way banks (free).
// ---------------------------------------------------------------------------
template <int ACT>
__global__ __launch_bounds__(256) void gemm_bf16_kernel(const unsigned short* __restrict__ A,
                                                        const unsigned short* __restrict__ Bt,
                                                        const float* __restrict__ bias,
                                                        float* __restrict__ C,
                                                        int M, int N, int K) {
    __shared__ __align__(16) unsigned short As[128 * 32];
    __shared__ __align__(16) unsigned short Bs[128 * 32];
    int t = threadIdx.x;
    int lane = t & 63, w = t >> 6;
    int wrow = w >> 1, wcol = w & 1;
    int quad = lane >> 4, l16 = lane & 15;
    int bm = blockIdx.y * 128, bn = blockIdx.x * 128;

    f32x4 acc[4][4];
#pragma unroll
    for (int i = 0; i < 4; i++)
#pragma unroll
        for (int j = 0; j < 4; j++)
            acc[i][j] = (f32x4){0.f, 0.f, 0.f, 0.f};

    // staging: wave w covers rows [w*16, w*16+16) (+64 for second half)
    int swz_s = ((lane >> 2) & 3) ^ ((lane >> 4) & 3);
    int gsel = ((lane & 3) ^ swz_s) * 8;                 // element offset of 16B group
    const unsigned short* a0 = A  + (size_t)(bm + w * 16 + (lane >> 2)) * K + gsel;
    const unsigned short* a1 = a0 + (size_t)64 * K;
    const unsigned short* b0 = Bt + (size_t)(bn + w * 16 + (lane >> 2)) * K + gsel;
    const unsigned short* b1 = b0 + (size_t)64 * K;
    unsigned short* lA0 = &As[(w * 16) * 32];
    unsigned short* lA1 = &As[(64 + w * 16) * 32];
    unsigned short* lB0 = &Bs[(w * 16) * 32];
    unsigned short* lB1 = &Bs[(64 + w * 16) * 32];

    // fragment read: row = (base mult of 16) + l16 -> swz depends only on l16
    int swz_f = (l16 & 3) ^ ((l16 >> 2) & 3);
    int foff = (quad ^ swz_f) * 8;

    for (int k0 = 0; k0 < K; k0 += 32) {
        __syncthreads();
        gll16(a0 + k0, lA0);
        gll16(a1 + k0, lA1);
        gll16(b0 + k0, lB0);
        gll16(b1 + k0, lB1);
        __syncthreads();   // compiler emits s_waitcnt vmcnt(0) before s_barrier
        bf16x8 af[4], bfr[4];
#pragma unroll
        for (int mi = 0; mi < 4; mi++)
            af[mi] = *(const bf16x8*)&As[(wrow * 64 + mi * 16 + l16) * 32 + foff];
#pragma unroll
        for (int ni = 0; ni < 4; ni++)
            bfr[ni] = *(const bf16x8*)&Bs[(wcol * 64 + ni * 16 + l16) * 32 + foff];
#pragma unroll
        for (int mi = 0; mi < 4; mi++)
#pragma unroll
            for (int ni = 0; ni < 4; ni++)
                acc[mi][ni] = __builtin_amdgcn_mfma_f32_16x16x32_bf16(af[mi], bfr[ni], acc[mi][ni], 0, 0, 0);
    }

#pragma unroll
    for (int mi = 0; mi < 4; mi++) {
#pragma unroll
        for (int r = 0; r < 4; r++) {
            int row = bm + wrow * 64 + mi * 16 + quad * 4 + r;
#pragma unroll
            for (int ni = 0; ni < 4; ni++) {
                int col = bn + wcol * 64 + ni * 16 + l16;
                float v = acc[mi][ni][r];
                if (ACT == 0) v += bias[col];
                else          v = v * sigmoidf_(v);  // silu
                C[(size_t)row * N + col] = v;
            }
        }
    }
}

// ---------------------------------------------------------------------------
// Kernel 3: gate: params = h1[BL,128] @ Wb2[128,60]; writes 1+gate (ws) + gate (out)
// ---------------------------------------------------------------------------
__global__ __launch_bounds__(256) void gate_kernel(const float* __restrict__ h1,
                                                   const float* __restrict__ Wb2,
                                                   const float* __restrict__ temperature,
                                                   float* __restrict__ gate_ws,
                                                   float* __restrict__ gate_out) {
    __shared__ float w2s[RR * 60];
    __shared__ float h1s[4][RR];
    __shared__ float ps[4][60];
    int t = threadIdx.x;
    for (int i = t; i < RR * 60; i += 256) w2s[i] = Wb2[i];
    int rr = t >> 6, lane = t & 63;
    int row = blockIdx.x * 4 + rr;
    h1s[rr][lane]      = h1[(size_t)row * RR + lane];
    h1s[rr][64 + lane] = h1[(size_t)row * RR + 64 + lane];
    __syncthreads();
    if (lane < 60) {
        float acc = 0.f;
#pragma unroll 8
        for (int k = 0; k < RR; k++) acc += h1s[rr][k] * w2s[k * 60 + lane];
        ps[rr][lane] = acc;
    }
    __syncthreads();
    if (lane < HH) {
        float p0 = ps[rr][lane * 5 + 0];
        float p1 = ps[rr][lane * 5 + 1];
        float p2 = ps[rr][lane * 5 + 2];
        float p3 = ps[rr][lane * 5 + 3];
        float temp = fminf(fmaxf(temperature[0], 0.1f), 2.0f);
        float sa = sigmoidf_(p0);
        float sp = tanhf(p1) * PI_F;
        float ca = sigmoidf_(p2);
        float cp = tanhf(p3) * PI_F;
        float itf = tanhf(sa * ca * cosf(sp - cp)) * temp;
        float gt = sigmoidf_(itf);
        size_t gi = (size_t)row * HH + lane;
        gate_ws[gi] = 1.0f + gt;
        gate_out[gi] = gt;
    }
}

// ---------------------------------------------------------------------------
// Kernel 4 (fused pass A+B): per (b,h), walk all 8 chunks keeping running
// state in registers; write EXCLUSIVE prefix per chunk, then accumulate.
// grid = B*H = 48; thread: e = t&63, wave g = t>>6 owns S rows g*16..+15.
// ---------------------------------------------------------------------------
__global__ __launch_bounds__(256) void passAB_kernel(const float* __restrict__ qkv,
                                                     const float* __restrict__ gate_ws,
                                                     float* __restrict__ states) {
    int bh = blockIdx.x;
    int b = bh / HH, h = bh % HH;
    __shared__ float Ks[CT][DH];
    __shared__ float Vs[CT][DH];
    __shared__ float wsm[CT];
    int t = threadIdx.x;
    int e = t & 63, g = t >> 6;
    float S[16] = {};
    float z = 0.f;
    for (int c = 0; c < NC; c++) {
        __syncthreads();   // protect LDS from previous chunk's readers
#pragma unroll
        for (int i = 0; i < 4; i++) {
            int fid = i * 256 + t;
            int j = fid >> 4, f = fid & 15;
            size_t row = (size_t)b * LL + c * CT + j;
            float4 k4 = *(const float4*)&qkv[row * D3 + DD + h * DH + f * 4];
            float4 v4 = *(const float4*)&qkv[row * D3 + 2 * DD + h * DH + f * 4];
            Ks[j][f * 4 + 0] = elu1f_(k4.x);
            Ks[j][f * 4 + 1] = elu1f_(k4.y);
            Ks[j][f * 4 + 2] = elu1f_(k4.z);
            Ks[j][f * 4 + 3] = elu1f_(k4.w);
            *(float4*)&Vs[j][f * 4] = v4;
        }
        if (t < CT) wsm[t] = gate_ws[((size_t)b * LL + c * CT + t) * HH + h];
        __syncthreads();
        // write exclusive prefix for this chunk
        float* st = states + (size_t)(bh * NC + c) * 4160;
#pragma unroll
        for (int i = 0; i < 16; i++) st[(g * 16 + i) * 64 + e] = S[i];
        if (g == 0) st[4096 + e] = z;
        // accumulate this chunk
        for (int j = 0; j < CT; j++) {
            float vw = Vs[j][e] * wsm[j];
#pragma unroll
            for (int i = 0; i < 16; i++) S[i] += Ks[j][g * 16 + i] * vw;
        }
        if (g == 0) {
            for (int j = 0; j < CT; j++) z += Ks[j][e];
        }
    }
}

// ---------------------------------------------------------------------------
// Kernel 5 (pass C + head-LN fused): replay chunk, out=num/den, then LN over
// DH=64 in-block (output tile parked in dead Vs rows), write bf16.
// thread: e = t>>2 (0..63), g = t&3 (k-quarter, shfl-reduced).
// ---------------------------------------------------------------------------
__global__ __launch_bounds__(256) void passC_kernel(const float* __restrict__ qkv,
                                                    const float* __restrict__ gate_ws,
                                                    const float* __restrict__ states,
                                                    const float* __restrict__ mg,
                                                    const float* __restrict__ mb,
                                                    unsigned short* __restrict__ attn_bf) {
    int blk = blockIdx.x;
    int c = blk % NC, bh = blk / NC;
    int b = bh / HH, h = bh % HH;
    __shared__ float Qs[CT][DH];
    __shared__ float Ks[CT][DH];
    __shared__ float Vs[CT][DH];
    __shared__ float wsm[CT];
    int t = threadIdx.x;
#pragma unroll
    for (int i = 0; i < 4; i++) {
        int fid = i * 256 + t;
        int j = fid >> 4, f = fid & 15;
        size_t row = (size_t)b * LL + c * CT + j;
        float4 q4 = *(const float4*)&qkv[row * D3 + h * DH + f * 4];
        float4 k4 = *(const float4*)&qkv[row * D3 + DD + h * DH + f * 4];
        float4 v4 = *(const float4*)&qkv[row * D3 + 2 * DD + h * DH + f * 4];
        Qs[j][f * 4 + 0] = elu1f_(q4.x);
        Qs[j][f * 4 + 1] = elu1f_(q4.y);
        Qs[j][f * 4 + 2] = elu1f_(q4.z);
        Qs[j][f * 4 + 3] = elu1f_(q4.w);
        Ks[j][f * 4 + 0] = elu1f_(k4.x);
        Ks[j][f * 4 + 1] = elu1f_(k4.y);
        Ks[j][f * 4 + 2] = elu1f_(k4.z);
        Ks[j][f * 4 + 3] = elu1f_(k4.w);
        *(float4*)&Vs[j][f * 4] = v4;
    }
    if (t < CT) wsm[t] = gate_ws[((size_t)b * LL + c * CT + t) * HH + h];
    __syncthreads();
    int e = t >> 2, g = t & 3;
    const float* st = states + (size_t)(bh * NC + c) * 4160;
    float S[16], z[16];
#pragma unroll
    for (int i = 0; i < 16; i++) {
        S[i] = st[(g * 16 + i) * 64 + e];
        z[i] = st[4096 + g * 16 + i];
    }
    for (int j = 0; j < CT; j++) {
        float vw = Vs[j][e] * wsm[j];
        float num = 0.f, den = 0.f;
#pragma unroll
        for (int i = 0; i < 16; i++) {
            float kk = Ks[j][g * 16 + i];
            float qq = Qs[j][g * 16 + i];
            S[i] += kk * vw;
            z[i] += kk;
            num += qq * S[i];
            den += qq * z[i];
        }
        num += __shfl_xor(num, 1);
        num += __shfl_xor(num, 2);
        den += __shfl_xor(den, 1);
        den += __shfl_xor(den, 2);
        // Vs[j] is dead after this iteration; park the output row there.
        // Each wave only touches its own e-columns -> no cross-wave hazard.
        if (g == 0) Vs[j][e] = num / (den + 1e-6f);
    }
    __syncthreads();
    // head-LN: 4 threads per row; row = t>>2, quarter c4 = t&3
    int row = t >> 2, c4 = t & 3;
    float vv[16];
    float s = 0.f, s2 = 0.f;
#pragma unroll
    for (int i = 0; i < 16; i++) {
        vv[i] = Vs[row][c4 * 16 + i];
        s += vv[i];
        s2 += vv[i] * vv[i];
    }
    s  += __shfl_xor(s, 1);  s  += __shfl_xor(s, 2);
    s2 += __shfl_xor(s2, 1); s2 += __shfl_xor(s2, 2);
    float mu = s * (1.0f / DH);
    float var = s2 * (1.0f / DH) - mu * mu;
    float rstd = rsqrtf(var + 1e-5f);
    float ov[16];
#pragma unroll
    for (int i = 0; i < 16; i++) {
        int col = c4 * 16 + i;
        ov[i] = (vv[i] - mu) * rstd * mg[col] + mb[col];
    }
    size_t gbase = ((size_t)b * LL + c * CT + row) * DD + h * DH + c4 * 16;
    int4 o0, o1;
    o0.x = packbf2(ov[0], ov[1]);   o0.y = packbf2(ov[2], ov[3]);
    o0.z = packbf2(ov[4], ov[5]);   o0.w = packbf2(ov[6], ov[7]);
    o1.x = packbf2(ov[8], ov[9]);   o1.y = packbf2(ov[10], ov[11]);
    o1.z = packbf2(ov[12], ov[13]); o1.w = packbf2(ov[14], ov[15]);
    *(int4*)&attn_bf[gbase]     = o0;
    *(int4*)&attn_bf[gbase + 8] = o1;
}

// ---------------------------------------------------------------------------
extern "C" void kernel_launch(void* const* d_in, const int* in_sizes, int n_in,
                              void* d_out, int out_size, void* d_ws, size_t ws_size,
                              hipStream_t stream) {
    const float* x    = (const float*)d_in[0];
    const float* Wqkv = (const float*)d_in[1];
    const float* bqkv = (const float*)d_in[2];
    const float* Wb1  = (const float*)d_in[3];
    const float* Wb2  = (const float*)d_in[4];
    const float* temperature = (const float*)d_in[5];
    const float* Wproj = (const float*)d_in[6];
    const float* bproj = (const float*)d_in[7];
    const float* ln_g = (const float*)d_in[8];
    const float* ln_b = (const float*)d_in[9];
    const float* mn_g = (const float*)d_in[10];
    const float* mn_b = (const float*)d_in[11];

    float* out0     = (float*)d_out;                    // (B,L,D)
    float* gate_out = out0 + (size_t)BL * DD;           // (B,L,H)

    float* ws = (float*)d_ws;
    float* qkv    = ws;                                   // 4,718,592 f32
    float* h1     = qkv + (size_t)BL * D3;                //   262,144
    float* gate   = h1 + (size_t)BL * RR;                 //    24,576 (holds 1+g)
    float* states = gate + (size_t)BL * HH;               // 1,597,440
    unsigned short* xnbf  = (unsigned short*)(states + (size_t)BB * HH * NC * 4160);
    unsigned short* xbf    = xnbf + (size_t)BL * DD;
    unsigned short* attnbf = xbf + (size_t)BL * DD;
    unsigned short* wqkvt  = attnbf + (size_t)BL * DD;
    unsigned short* wb1t   = wqkvt + (size_t)D3 * DD;
    unsigned short* wprojt = wb1t + (size_t)DD * RR;

    // 1. x_norm (bf16) + raw x (bf16), one pass
    ln_row_kernel<<<BL, 256, 0, stream>>>(x, ln_g, ln_b, xnbf, xbf);
    // 2. all weight transposes
    transpose_all_kernel<<<2400, 256, 0, stream>>>(Wqkv, Wb1, Wproj, wqkvt, wb1t, wprojt);
    // 3. qkv = x_norm @ Wqkv + bqkv
    gemm_bf16_kernel<0><<<dim3(D3 / 128, BL / 128), 256, 0, stream>>>(xnbf, wqkvt, bqkv, qkv, BL, D3, DD);
    // 4. h1 = silu(x @ Wb1)
    gemm_bf16_kernel<1><<<dim3(RR / 128, BL / 128), 256, 0, stream>>>(xbf, wb1t, nullptr, h1, BL, RR, DD);
    // 5. gate
    gate_kernel<<<BL / 4, 256, 0, stream>>>(h1, Wb2, temperature, gate, gate_out);
    // 6. fused local-state + prefix scan
    passAB_kernel<<<BB * HH, 256, 0, stream>>>(qkv, gate, states);
    // 7. replay + head-LN -> bf16
    passC_kernel<<<BB * HH * NC, 256, 0, stream>>>(qkv, gate, states, mn_g, mn_b, attnbf);
    // 8. out = attn @ Wproj + bproj
    gemm_bf16_kernel<0><<<dim3(DD / 128, BL / 128), 256, 0, stream>>>(attnbf, wprojt, bproj, out0, BL, DD, DD);
}

// Round 4
// 184.640 us; speedup vs baseline: 1.2698x; 1.2698x over previous
//
#include <hip/hip_runtime.h>
#include <hip/hip_bf16.h>
#include <math.h>

// Problem constants
#define BB 4
#define LL 512
#define DD 768
#define HH 12
#define DH 64
#define RR 128
#define BL (BB*LL)      // 2048
#define D3 (3*DD)       // 2304
#define NC 8            // chunks over L
#define CT 64           // chunk length
#define PI_F 3.14159265358979323846f

typedef short bf16x8 __attribute__((ext_vector_type(8)));
typedef float f32x4 __attribute__((ext_vector_type(4)));

__device__ __forceinline__ float sigmoidf_(float x) { return 1.0f / (1.0f + expf(-x)); }
__device__ __forceinline__ float elu1f_(float x)    { return x > 0.0f ? x + 1.0f : expf(x); }
__device__ __forceinline__ unsigned short f2bf(float f) {
    unsigned u = __float_as_uint(f);
    unsigned r = u + 0x7FFF + ((u >> 16) & 1);
    return (unsigned short)(r >> 16);
}
__device__ __forceinline__ int packbf2(float lo, float hi) {
    return (int)f2bf(lo) | ((int)f2bf(hi) << 16);
}
// async global->LDS DMA, 16 B per lane; LDS dst = wave-uniform base + lane*16
__device__ __forceinline__ void gll16(const void* g, void* l) {
    __builtin_amdgcn_global_load_lds(
        (const __attribute__((address_space(1))) void*)g,
        (__attribute__((address_space(3))) void*)l, 16, 0, 0);
}

// ---------------------------------------------------------------------------
// Kernel 1 (prep, fused): bid<2048 -> row-LN of x (bf16) + raw x (bf16);
// bid>=2048 -> weight transposes f32 [K][N] -> bf16 [N][K].
// ---------------------------------------------------------------------------
__global__ __launch_bounds__(256) void prep_kernel(const float* __restrict__ x,
                                                   const float* __restrict__ g,
                                                   const float* __restrict__ b,
                                                   unsigned short* __restrict__ xn,
                                                   unsigned short* __restrict__ xb,
                                                   const float* __restrict__ Wqkv,
                                                   const float* __restrict__ Wb1,
                                                   const float* __restrict__ Wproj,
                                                   unsigned short* __restrict__ wqkvt,
                                                   unsigned short* __restrict__ wb1t,
                                                   unsigned short* __restrict__ wprojt) {
    __shared__ float smem[32 * 33];
    int bid = blockIdx.x;
    int t = threadIdx.x;
    if (bid < 2048) {
        // ---- row layernorm over D=768 ----
        int row = bid;
        int w = t >> 6, lane = t & 63;
        float v[3];
        float s = 0.f, s2 = 0.f;
#pragma unroll
        for (int i = 0; i < 3; i++) {
            v[i] = x[(size_t)row * DD + t + i * 256];
            s += v[i];
            s2 += v[i] * v[i];
        }
#pragma unroll
        for (int off = 1; off < 64; off <<= 1) {
            s  += __shfl_xor(s, off);
            s2 += __shfl_xor(s2, off);
        }
        if (lane == 0) { smem[w] = s; smem[4 + w] = s2; }
        __syncthreads();
        s  = smem[0] + smem[1] + smem[2] + smem[3];
        s2 = smem[4] + smem[5] + smem[6] + smem[7];
        float mu = s * (1.0f / DD);
        float var = s2 * (1.0f / DD) - mu * mu;
        float rstd = rsqrtf(var + 1e-5f);
#pragma unroll
        for (int i = 0; i < 3; i++) {
            int col = t + i * 256;
            xn[(size_t)row * DD + col] = f2bf((v[i] - mu) * rstd * g[col] + b[col]);
            xb[(size_t)row * DD + col] = f2bf(v[i]);
        }
    } else {
        // ---- transpose ----
        bid -= 2048;
        const float* in; unsigned short* out; int K, N, bx, by;
        if (bid < 1728)      { in = Wqkv;  out = wqkvt;  K = DD; N = D3; bx = bid % 72; by = bid / 72; }
        else if (bid < 1824) { bid -= 1728; in = Wb1;  out = wb1t;  K = DD; N = RR; bx = bid % 4;  by = bid / 4; }
        else                 { bid -= 1824; in = Wproj; out = wprojt; K = DD; N = DD; bx = bid % 24; by = bid / 24; }
        int n0 = bx * 32, k0 = by * 32;
        int tx = t & 31, ty = t >> 5;   // ty 0..7
        float (*tile)[33] = (float(*)[33])smem;
#pragma unroll
        for (int i = 0; i < 4; i++)
            tile[ty + i * 8][tx] = in[(size_t)(k0 + ty + i * 8) * N + n0 + tx];
        __syncthreads();
#pragma unroll
        for (int i = 0; i < 4; i++)
            out[(size_t)(n0 + ty + i * 8) * K + k0 + tx] = f2bf(tile[tx][ty + i * 8]);
    }
}

// ---------------------------------------------------------------------------
// Kernel 2 (fused QKV + Wb1 GEMM): 128x128 tile, gll16 staging, XOR-swizzled
// unpadded LDS. Blocks 0..287: qkv = xn @ Wqkv + bqkv. Blocks 288..303:
// h1 = silu(xb @ Wb1). K = 768 for both.
// ---------------------------------------------------------------------------
__global__ __launch_bounds__(256) void gemm_big_kernel(const unsigned short* __restrict__ xn,
                                                       const unsigned short* __restrict__ wqkvt,
                                                       const float* __restrict__ bqkv,
                                                       float* __restrict__ qkv,
                                                       const unsigned short* __restrict__ xb,
                                                       const unsigned short* __restrict__ wb1t,
                                                       float* __restrict__ h1) {
    __shared__ __align__(16) unsigned short As[128 * 32];
    __shared__ __align__(16) unsigned short Bs[128 * 32];
    int bid = blockIdx.x;
    const unsigned short *A, *Bt;
    const float* bias;
    float* C;
    int N, act, bm, bn;
    if (bid < 288) { A = xn; Bt = wqkvt; bias = bqkv; C = qkv; N = D3; act = 0;
                     bn = (bid % 18) * 128; bm = (bid / 18) * 128; }
    else           { int b2 = bid - 288; A = xb; Bt = wb1t; bias = nullptr; C = h1; N = RR; act = 1;
                     bm = b2 * 128; bn = 0; }
    const int K = DD;

    int t = threadIdx.x;
    int lane = t & 63, w = t >> 6;
    int wrow = w >> 1, wcol = w & 1;
    int quad = lane >> 4, l16 = lane & 15;

    f32x4 acc[4][4];
#pragma unroll
    for (int i = 0; i < 4; i++)
#pragma unroll
        for (int j = 0; j < 4; j++)
            acc[i][j] = (f32x4){0.f, 0.f, 0.f, 0.f};

    int swz_s = ((lane >> 2) & 3) ^ ((lane >> 4) & 3);
    int gsel = ((lane & 3) ^ swz_s) * 8;
    const unsigned short* a0 = A  + (size_t)(bm + w * 16 + (lane >> 2)) * K + gsel;
    const unsigned short* a1 = a0 + (size_t)64 * K;
    const unsigned short* b0 = Bt + (size_t)(bn + w * 16 + (lane >> 2)) * K + gsel;
    const unsigned short* b1 = b0 + (size_t)64 * K;
    unsigned short* lA0 = &As[(w * 16) * 32];
    unsigned short* lA1 = &As[(64 + w * 16) * 32];
    unsigned short* lB0 = &Bs[(w * 16) * 32];
    unsigned short* lB1 = &Bs[(64 + w * 16) * 32];

    int swz_f = (l16 & 3) ^ ((l16 >> 2) & 3);
    int foff = (quad ^ swz_f) * 8;

    for (int k0 = 0; k0 < K; k0 += 32) {
        __syncthreads();
        gll16(a0 + k0, lA0);
        gll16(a1 + k0, lA1);
        gll16(b0 + k0, lB0);
        gll16(b1 + k0, lB1);
        __syncthreads();
        bf16x8 af[4], bfr[4];
#pragma unroll
        for (int mi = 0; mi < 4; mi++)
            af[mi] = *(const bf16x8*)&As[(wrow * 64 + mi * 16 + l16) * 32 + foff];
#pragma unroll
        for (int ni = 0; ni < 4; ni++)
            bfr[ni] = *(const bf16x8*)&Bs[(wcol * 64 + ni * 16 + l16) * 32 + foff];
#pragma unroll
        for (int mi = 0; mi < 4; mi++)
#pragma unroll
            for (int ni = 0; ni < 4; ni++)
                acc[mi][ni] = __builtin_amdgcn_mfma_f32_16x16x32_bf16(af[mi], bfr[ni], acc[mi][ni], 0, 0, 0);
    }

#pragma unroll
    for (int mi = 0; mi < 4; mi++) {
#pragma unroll
        for (int r = 0; r < 4; r++) {
            int row = bm + wrow * 64 + mi * 16 + quad * 4 + r;
#pragma unroll
            for (int ni = 0; ni < 4; ni++) {
                int col = bn + wcol * 64 + ni * 16 + l16;
                float v = acc[mi][ni][r];
                if (act == 0) v += bias[col];
                else          v = v * sigmoidf_(v);  // silu
                C[(size_t)row * N + col] = v;
            }
        }
    }
}

// ---------------------------------------------------------------------------
// Kernel 2b: 64x64-tile GEMM for proj (N=768 -> 384 blocks). Same structure.
// ---------------------------------------------------------------------------
__global__ __launch_bounds__(256) void gemm64_kernel(const unsigned short* __restrict__ A,
                                                     const unsigned short* __restrict__ Bt,
                                                     const float* __restrict__ bias,
                                                     float* __restrict__ C,
                                                     int M, int N, int K) {
    __shared__ __align__(16) unsigned short As[64 * 32];
    __shared__ __align__(16) unsigned short Bs[64 * 32];
    int t = threadIdx.x;
    int lane = t & 63, w = t >> 6;
    int wrow = w >> 1, wcol = w & 1;
    int quad = lane >> 4, l16 = lane & 15;
    int bm = blockIdx.y * 64, bn = blockIdx.x * 64;

    f32x4 acc[2][2];
#pragma unroll
    for (int i = 0; i < 2; i++)
#pragma unroll
        for (int j = 0; j < 2; j++)
            acc[i][j] = (f32x4){0.f, 0.f, 0.f, 0.f};

    int swz_s = ((lane >> 2) & 3) ^ ((lane >> 4) & 3);
    int gsel = ((lane & 3) ^ swz_s) * 8;
    const unsigned short* a0 = A  + (size_t)(bm + w * 16 + (lane >> 2)) * K + gsel;
    const unsigned short* b0 = Bt + (size_t)(bn + w * 16 + (lane >> 2)) * K + gsel;
    unsigned short* lA0 = &As[(w * 16) * 32];
    unsigned short* lB0 = &Bs[(w * 16) * 32];

    int swz_f = (l16 & 3) ^ ((l16 >> 2) & 3);
    int foff = (quad ^ swz_f) * 8;

    for (int k0 = 0; k0 < K; k0 += 32) {
        __syncthreads();
        gll16(a0 + k0, lA0);
        gll16(b0 + k0, lB0);
        __syncthreads();
        bf16x8 af[2], bfr[2];
#pragma unroll
        for (int mi = 0; mi < 2; mi++)
            af[mi] = *(const bf16x8*)&As[(wrow * 32 + mi * 16 + l16) * 32 + foff];
#pragma unroll
        for (int ni = 0; ni < 2; ni++)
            bfr[ni] = *(const bf16x8*)&Bs[(wcol * 32 + ni * 16 + l16) * 32 + foff];
#pragma unroll
        for (int mi = 0; mi < 2; mi++)
#pragma unroll
            for (int ni = 0; ni < 2; ni++)
                acc[mi][ni] = __builtin_amdgcn_mfma_f32_16x16x32_bf16(af[mi], bfr[ni], acc[mi][ni], 0, 0, 0);
    }

#pragma unroll
    for (int mi = 0; mi < 2; mi++) {
#pragma unroll
        for (int r = 0; r < 4; r++) {
            int row = bm + wrow * 32 + mi * 16 + quad * 4 + r;
#pragma unroll
            for (int ni = 0; ni < 2; ni++) {
                int col = bn + wcol * 32 + ni * 16 + l16;
                C[(size_t)row * N + col] = acc[mi][ni][r] + bias[col];
            }
        }
    }
}

// ---------------------------------------------------------------------------
// Kernel 3: gate: params = h1[BL,128] @ Wb2[128,60]; writes 1+gate (ws) + gate (out)
// ---------------------------------------------------------------------------
__global__ __launch_bounds__(256) void gate_kernel(const float* __restrict__ h1,
                                                   const float* __restrict__ Wb2,
                                                   const float* __restrict__ temperature,
                                                   float* __restrict__ gate_ws,
                                                   float* __restrict__ gate_out) {
    __shared__ float w2s[RR * 60];
    __shared__ float h1s[4][RR];
    __shared__ float ps[4][60];
    int t = threadIdx.x;
    for (int i = t; i < RR * 60; i += 256) w2s[i] = Wb2[i];
    int rr = t >> 6, lane = t & 63;
    int row = blockIdx.x * 4 + rr;
    h1s[rr][lane]      = h1[(size_t)row * RR + lane];
    h1s[rr][64 + lane] = h1[(size_t)row * RR + 64 + lane];
    __syncthreads();
    if (lane < 60) {
        float acc = 0.f;
#pragma unroll 8
        for (int k = 0; k < RR; k++) acc += h1s[rr][k] * w2s[k * 60 + lane];
        ps[rr][lane] = acc;
    }
    __syncthreads();
    if (lane < HH) {
        float p0 = ps[rr][lane * 5 + 0];
        float p1 = ps[rr][lane * 5 + 1];
        float p2 = ps[rr][lane * 5 + 2];
        float p3 = ps[rr][lane * 5 + 3];
        float temp = fminf(fmaxf(temperature[0], 0.1f), 2.0f);
        float sa = sigmoidf_(p0);
        float sp = tanhf(p1) * PI_F;
        float ca = sigmoidf_(p2);
        float cp = tanhf(p3) * PI_F;
        float itf = tanhf(sa * ca * cosf(sp - cp)) * temp;
        float gt = sigmoidf_(itf);
        size_t gi = (size_t)row * HH + lane;
        gate_ws[gi] = 1.0f + gt;
        gate_out[gi] = gt;
    }
}

// ---------------------------------------------------------------------------
// Kernel 4 (pass A): per-chunk LOCAL state S_c = sum_j w_j k_j v_j^T and
// z_c = sum_j k_j.  grid = B*H*NC = 384 blocks.
// ---------------------------------------------------------------------------
__global__ __launch_bounds__(256) void passA_kernel(const float* __restrict__ qkv,
                                                    const float* __restrict__ gate_ws,
                                                    float* __restrict__ states) {
    int blk = blockIdx.x;
    int c = blk % NC, bh = blk / NC;
    int b = bh / HH, h = bh % HH;
    __shared__ float Ks[CT][DH];
    __shared__ float Vs[CT][DH];
    __shared__ float wsm[CT];
    int t = threadIdx.x;
#pragma unroll
    for (int i = 0; i < 4; i++) {
        int fid = i * 256 + t;
        int j = fid >> 4, f = fid & 15;
        size_t row = (size_t)b * LL + c * CT + j;
        float4 k4 = *(const float4*)&qkv[row * D3 + DD + h * DH + f * 4];
        float4 v4 = *(const float4*)&qkv[row * D3 + 2 * DD + h * DH + f * 4];
        Ks[j][f * 4 + 0] = elu1f_(k4.x);
        Ks[j][f * 4 + 1] = elu1f_(k4.y);
        Ks[j][f * 4 + 2] = elu1f_(k4.z);
        Ks[j][f * 4 + 3] = elu1f_(k4.w);
        *(float4*)&Vs[j][f * 4] = v4;
    }
    if (t < CT) wsm[t] = gate_ws[((size_t)b * LL + c * CT + t) * HH + h];
    __syncthreads();
    int e = t & 63, g = t >> 6;
    float S[16] = {};
    for (int j = 0; j < CT; j++) {
        float vw = Vs[j][e] * wsm[j];
#pragma unroll
        for (int i = 0; i < 16; i++) S[i] += Ks[j][g * 16 + i] * vw;
    }
    float* st = states + (size_t)(bh * NC + c) * 4160;
#pragma unroll
    for (int i = 0; i < 16; i++) st[(g * 16 + i) * 64 + e] = S[i];
    if (g == 0) {
        float z = 0.f;
        for (int j = 0; j < CT; j++) z += Ks[j][e];
        st[4096 + e] = z;
    }
}

// ---------------------------------------------------------------------------
// Kernel 5 (pass C + head-LN fused): init S,z by summing previous chunks'
// LOCAL states (exclusive prefix, replaces passB), replay chunk, head-LN,
// write bf16.  thread: e = t>>2 (0..63), g = t&3 (k-quarter).
// ---------------------------------------------------------------------------
__global__ __launch_bounds__(256) void passC_kernel(const float* __restrict__ qkv,
                                                    const float* __restrict__ gate_ws,
                                                    const float* __restrict__ states,
                                                    const float* __restrict__ mg,
                                                    const float* __restrict__ mb,
                                                    unsigned short* __restrict__ attn_bf) {
    int blk = blockIdx.x;
    int c = blk % NC, bh = blk / NC;
    int b = bh / HH, h = bh % HH;
    __shared__ float Qs[CT][DH];
    __shared__ float Ks[CT][DH];
    __shared__ float Vs[CT][DH];
    __shared__ float wsm[CT];
    int t = threadIdx.x;
#pragma unroll
    for (int i = 0; i < 4; i++) {
        int fid = i * 256 + t;
        int j = fid >> 4, f = fid & 15;
        size_t row = (size_t)b * LL + c * CT + j;
        float4 q4 = *(const float4*)&qkv[row * D3 + h * DH + f * 4];
        float4 k4 = *(const float4*)&qkv[row * D3 + DD + h * DH + f * 4];
        float4 v4 = *(const float4*)&qkv[row * D3 + 2 * DD + h * DH + f * 4];
        Qs[j][f * 4 + 0] = elu1f_(q4.x);
        Qs[j][f * 4 + 1] = elu1f_(q4.y);
        Qs[j][f * 4 + 2] = elu1f_(q4.z);
        Qs[j][f * 4 + 3] = elu1f_(q4.w);
        Ks[j][f * 4 + 0] = elu1f_(k4.x);
        Ks[j][f * 4 + 1] = elu1f_(k4.y);
        Ks[j][f * 4 + 2] = elu1f_(k4.z);
        Ks[j][f * 4 + 3] = elu1f_(k4.w);
        *(float4*)&Vs[j][f * 4] = v4;
    }
    if (t < CT) wsm[t] = gate_ws[((size_t)b * LL + c * CT + t) * HH + h];
    __syncthreads();
    int e = t >> 2, g = t & 3;
    float S[16] = {}, z[16] = {};
    for (int cp = 0; cp < c; cp++) {
        const float* st = states + (size_t)(bh * NC + cp) * 4160;
#pragma unroll
        for (int i = 0; i < 16; i++) {
            S[i] += st[(g * 16 + i) * 64 + e];
            z[i] += st[4096 + g * 16 + i];
        }
    }
    for (int j = 0; j < CT; j++) {
        float vw = Vs[j][e] * wsm[j];
        float num = 0.f, den = 0.f;
#pragma unroll
        for (int i = 0; i < 16; i++) {
            float kk = Ks[j][g * 16 + i];
            float qq = Qs[j][g * 16 + i];
            S[i] += kk * vw;
            z[i] += kk;
            num += qq * S[i];
            den += qq * z[i];
        }
        num += __shfl_xor(num, 1);
        num += __shfl_xor(num, 2);
        den += __shfl_xor(den, 1);
        den += __shfl_xor(den, 2);
        // park output row in dead Vs row (each wave owns its e-columns)
        if (g == 0) Vs[j][e] = num / (den + 1e-6f);
    }
    __syncthreads();
    // head-LN: 4 threads per row
    int row = t >> 2, c4 = t & 3;
    float vv[16];
    float s = 0.f, s2 = 0.f;
#pragma unroll
    for (int i = 0; i < 16; i++) {
        vv[i] = Vs[row][c4 * 16 + i];
        s += vv[i];
        s2 += vv[i] * vv[i];
    }
    s  += __shfl_xor(s, 1);  s  += __shfl_xor(s, 2);
    s2 += __shfl_xor(s2, 1); s2 += __shfl_xor(s2, 2);
    float mu = s * (1.0f / DH);
    float var = s2 * (1.0f / DH) - mu * mu;
    float rstd = rsqrtf(var + 1e-5f);
    float ov[16];
#pragma unroll
    for (int i = 0; i < 16; i++) {
        int col = c4 * 16 + i;
        ov[i] = (vv[i] - mu) * rstd * mg[col] + mb[col];
    }
    size_t gbase = ((size_t)b * LL + c * CT + row) * DD + h * DH + c4 * 16;
    int4 o0, o1;
    o0.x = packbf2(ov[0], ov[1]);   o0.y = packbf2(ov[2], ov[3]);
    o0.z = packbf2(ov[4], ov[5]);   o0.w = packbf2(ov[6], ov[7]);
    o1.x = packbf2(ov[8], ov[9]);   o1.y = packbf2(ov[10], ov[11]);
    o1.z = packbf2(ov[12], ov[13]); o1.w = packbf2(ov[14], ov[15]);
    *(int4*)&attn_bf[gbase]     = o0;
    *(int4*)&attn_bf[gbase + 8] = o1;
}

// ---------------------------------------------------------------------------
extern "C" void kernel_launch(void* const* d_in, const int* in_sizes, int n_in,
                              void* d_out, int out_size, void* d_ws, size_t ws_size,
                              hipStream_t stream) {
    const float* x    = (const float*)d_in[0];
    const float* Wqkv = (const float*)d_in[1];
    const float* bqkv = (const float*)d_in[2];
    const float* Wb1  = (const float*)d_in[3];
    const float* Wb2  = (const float*)d_in[4];
    const float* temperature = (const float*)d_in[5];
    const float* Wproj = (const float*)d_in[6];
    const float* bproj = (const float*)d_in[7];
    const float* ln_g = (const float*)d_in[8];
    const float* ln_b = (const float*)d_in[9];
    const float* mn_g = (const float*)d_in[10];
    const float* mn_b = (const float*)d_in[11];

    float* out0     = (float*)d_out;                    // (B,L,D)
    float* gate_out = out0 + (size_t)BL * DD;           // (B,L,H)

    float* ws = (float*)d_ws;
    float* qkv    = ws;                                   // 4,718,592 f32
    float* h1     = qkv + (size_t)BL * D3;                //   262,144
    float* gate   = h1 + (size_t)BL * RR;                 //    24,576 (holds 1+g)
    float* states = gate + (size_t)BL * HH;               // 1,597,440
    unsigned short* xnbf  = (unsigned short*)(states + (size_t)BB * HH * NC * 4160);
    unsigned short* xbf    = xnbf + (size_t)BL * DD;
    unsigned short* attnbf = xbf + (size_t)BL * DD;
    unsigned short* wqkvt  = attnbf + (size_t)BL * DD;
    unsigned short* wb1t   = wqkvt + (size_t)D3 * DD;
    unsigned short* wprojt = wb1t + (size_t)DD * RR;

    // 1. LN + x->bf16 + all weight transposes (one launch)
    prep_kernel<<<4448, 256, 0, stream>>>(x, ln_g, ln_b, xnbf, xbf,
                                          Wqkv, Wb1, Wproj, wqkvt, wb1t, wprojt);
    // 2. qkv GEMM + Wb1 GEMM fused (304 blocks)
    gemm_big_kernel<<<304, 256, 0, stream>>>(xnbf, wqkvt, bqkv, qkv, xbf, wb1t, h1);
    // 3. gate
    gate_kernel<<<BL / 4, 256, 0, stream>>>(h1, Wb2, temperature, gate, gate_out);
    // 4. chunk-local states (384 blocks)
    passA_kernel<<<BB * HH * NC, 256, 0, stream>>>(qkv, gate, states);
    // 5. replay + inline prefix + head-LN -> bf16 (384 blocks)
    passC_kernel<<<BB * HH * NC, 256, 0, stream>>>(qkv, gate, states, mn_g, mn_b, attnbf);
    // 6. out = attn @ Wproj + bproj (64x64 tiles -> 384 blocks)
    gemm64_kernel<<<dim3(DD / 64, BL / 64), 256, 0, stream>>>(attnbf, wprojt, bproj, out0, BL, DD, DD);
}

// Round 8
// 154.291 us; speedup vs baseline: 1.5196x; 1.1967x over previous
//
#include <hip/hip_runtime.h>
#include <hip/hip_bf16.h>
#include <math.h>

// Problem constants
#define BB 4
#define LL 512
#define DD 768
#define HH 12
#define DH 64
#define RR 128
#define BL (BB*LL)      // 2048
#define D3 (3*DD)       // 2304
#define NC 8            // chunks over L
#define CT 64           // chunk length
#define SP 72           // LDS row stride (elems), 144 B, 16B-aligned rows
#define PI_F 3.14159265358979323846f

typedef short bf16x8 __attribute__((ext_vector_type(8)));
typedef _Float16 f16x8 __attribute__((ext_vector_type(8)));
typedef float f32x4 __attribute__((ext_vector_type(4)));

__device__ __forceinline__ float sigmoidf_(float x) { return 1.0f / (1.0f + expf(-x)); }
__device__ __forceinline__ float elu1f_(float x)    { return x > 0.0f ? x + 1.0f : expf(x); }
__device__ __forceinline__ unsigned short f2bf(float f) {
    unsigned u = __float_as_uint(f);
    unsigned r = u + 0x7FFF + ((u >> 16) & 1);
    return (unsigned short)(r >> 16);
}
// fp16 convert (RNE) + helpers
__device__ __forceinline__ unsigned short f2h(float f) {
    _Float16 h = (_Float16)f;
    return *(unsigned short*)&h;
}
__device__ __forceinline__ float h2f(unsigned short u) {
    _Float16 h = *(_Float16*)&u;
    return (float)h;
}
__device__ __forceinline__ int packh2(float lo, float hi) {
    return (int)f2h(lo) | ((int)f2h(hi) << 16);
}
// split fp32 -> fp16 hi + fp16 lo residual
__device__ __forceinline__ void splith(float v, unsigned short& h, unsigned short& l) {
    h = f2h(v);
    l = f2h(v - h2f(h));
}
// async global->LDS DMA, 16 B per lane
__device__ __forceinline__ void gll16(const void* g, void* l) {
    __builtin_amdgcn_global_load_lds(
        (const __attribute__((address_space(1))) void*)g,
        (__attribute__((address_space(3))) void*)l, 16, 0, 0);
}

// ---------------------------------------------------------------------------
// Kernel 1 (prep, fused): bid<2048 -> row-LN of x (bf16) + raw x (bf16);
// bid>=2048 -> weight transposes f32 [K][N] -> bf16 [N][K].
// ---------------------------------------------------------------------------
__global__ __launch_bounds__(256) void prep_kernel(const float* __restrict__ x,
                                                   const float* __restrict__ g,
                                                   const float* __restrict__ b,
                                                   unsigned short* __restrict__ xn,
                                                   unsigned short* __restrict__ xb,
                                                   const float* __restrict__ Wqkv,
                                                   const float* __restrict__ Wb1,
                                                   const float* __restrict__ Wproj,
                                                   unsigned short* __restrict__ wqkvt,
                                                   unsigned short* __restrict__ wb1t,
                                                   unsigned short* __restrict__ wprojt) {
    __shared__ float smem[32 * 33];
    int bid = blockIdx.x;
    int t = threadIdx.x;
    if (bid < 2048) {
        int row = bid;
        int w = t >> 6, lane = t & 63;
        float v[3];
        float s = 0.f, s2 = 0.f;
#pragma unroll
        for (int i = 0; i < 3; i++) {
            v[i] = x[(size_t)row * DD + t + i * 256];
            s += v[i];
            s2 += v[i] * v[i];
        }
#pragma unroll
        for (int off = 1; off < 64; off <<= 1) {
            s  += __shfl_xor(s, off);
            s2 += __shfl_xor(s2, off);
        }
        if (lane == 0) { smem[w] = s; smem[4 + w] = s2; }
        __syncthreads();
        s  = smem[0] + smem[1] + smem[2] + smem[3];
        s2 = smem[4] + smem[5] + smem[6] + smem[7];
        float mu = s * (1.0f / DD);
        float var = s2 * (1.0f / DD) - mu * mu;
        float rstd = rsqrtf(var + 1e-5f);
#pragma unroll
        for (int i = 0; i < 3; i++) {
            int col = t + i * 256;
            xn[(size_t)row * DD + col] = f2bf((v[i] - mu) * rstd * g[col] + b[col]);
            xb[(size_t)row * DD + col] = f2bf(v[i]);
        }
    } else {
        bid -= 2048;
        const float* in; unsigned short* out; int K, N, bx, by;
        if (bid < 1728)      { in = Wqkv;  out = wqkvt;  K = DD; N = D3; bx = bid % 72; by = bid / 72; }
        else if (bid < 1824) { bid -= 1728; in = Wb1;  out = wb1t;  K = DD; N = RR; bx = bid % 4;  by = bid / 4; }
        else                 { bid -= 1824; in = Wproj; out = wprojt; K = DD; N = DD; bx = bid % 24; by = bid / 24; }
        int n0 = bx * 32, k0 = by * 32;
        int tx = t & 31, ty = t >> 5;
        float (*tile)[33] = (float(*)[33])smem;
#pragma unroll
        for (int i = 0; i < 4; i++)
            tile[ty + i * 8][tx] = in[(size_t)(k0 + ty + i * 8) * N + n0 + tx];
        __syncthreads();
#pragma unroll
        for (int i = 0; i < 4; i++)
            out[(size_t)(n0 + ty + i * 8) * K + k0 + tx] = f2bf(tile[tx][ty + i * 8]);
    }
}

// ---------------------------------------------------------------------------
// Kernel 2 (fused QKV + Wb1 GEMM): 128x128 tile, gll16 staging, XOR-swizzled
// unpadded LDS. Blocks 0..287: qkv. Blocks 288..303: h1 = silu(xb @ Wb1).
// ---------------------------------------------------------------------------
__global__ __launch_bounds__(256) void gemm_big_kernel(const unsigned short* __restrict__ xn,
                                                       const unsigned short* __restrict__ wqkvt,
                                                       const float* __restrict__ bqkv,
                                                       float* __restrict__ qkv,
                                                       const unsigned short* __restrict__ xb,
                                                       const unsigned short* __restrict__ wb1t,
                                                       float* __restrict__ h1) {
    __shared__ __align__(16) unsigned short As[128 * 32];
    __shared__ __align__(16) unsigned short Bs[128 * 32];
    int bid = blockIdx.x;
    const unsigned short *A, *Bt;
    const float* bias;
    float* C;
    int N, act, bm, bn;
    if (bid < 288) { A = xn; Bt = wqkvt; bias = bqkv; C = qkv; N = D3; act = 0;
                     bn = (bid % 18) * 128; bm = (bid / 18) * 128; }
    else           { int b2 = bid - 288; A = xb; Bt = wb1t; bias = nullptr; C = h1; N = RR; act = 1;
                     bm = b2 * 128; bn = 0; }
    const int K = DD;

    int t = threadIdx.x;
    int lane = t & 63, w = t >> 6;
    int wrow = w >> 1, wcol = w & 1;
    int quad = lane >> 4, l16 = lane & 15;

    f32x4 acc[4][4];
#pragma unroll
    for (int i = 0; i < 4; i++)
#pragma unroll
        for (int j = 0; j < 4; j++)
            acc[i][j] = (f32x4){0.f, 0.f, 0.f, 0.f};

    int swz_s = ((lane >> 2) & 3) ^ ((lane >> 4) & 3);
    int gsel = ((lane & 3) ^ swz_s) * 8;
    const unsigned short* a0 = A  + (size_t)(bm + w * 16 + (lane >> 2)) * K + gsel;
    const unsigned short* a1 = a0 + (size_t)64 * K;
    const unsigned short* b0 = Bt + (size_t)(bn + w * 16 + (lane >> 2)) * K + gsel;
    const unsigned short* b1 = b0 + (size_t)64 * K;
    unsigned short* lA0 = &As[(w * 16) * 32];
    unsigned short* lA1 = &As[(64 + w * 16) * 32];
    unsigned short* lB0 = &Bs[(w * 16) * 32];
    unsigned short* lB1 = &Bs[(64 + w * 16) * 32];

    int swz_f = (l16 & 3) ^ ((l16 >> 2) & 3);
    int foff = (quad ^ swz_f) * 8;

    for (int k0 = 0; k0 < K; k0 += 32) {
        __syncthreads();
        gll16(a0 + k0, lA0);
        gll16(a1 + k0, lA1);
        gll16(b0 + k0, lB0);
        gll16(b1 + k0, lB1);
        __syncthreads();
        bf16x8 af[4], bfr[4];
#pragma unroll
        for (int mi = 0; mi < 4; mi++)
            af[mi] = *(const bf16x8*)&As[(wrow * 64 + mi * 16 + l16) * 32 + foff];
#pragma unroll
        for (int ni = 0; ni < 4; ni++)
            bfr[ni] = *(const bf16x8*)&Bs[(wcol * 64 + ni * 16 + l16) * 32 + foff];
#pragma unroll
        for (int mi = 0; mi < 4; mi++)
#pragma unroll
            for (int ni = 0; ni < 4; ni++)
                acc[mi][ni] = __builtin_amdgcn_mfma_f32_16x16x32_bf16(af[mi], bfr[ni], acc[mi][ni], 0, 0, 0);
    }

#pragma unroll
    for (int mi = 0; mi < 4; mi++) {
#pragma unroll
        for (int r = 0; r < 4; r++) {
            int row = bm + wrow * 64 + mi * 16 + quad * 4 + r;
#pragma unroll
            for (int ni = 0; ni < 4; ni++) {
                int col = bn + wcol * 64 + ni * 16 + l16;
                float v = acc[mi][ni][r];
                if (act == 0) v += bias[col];
                else          v = v * sigmoidf_(v);
                C[(size_t)row * N + col] = v;
            }
        }
    }
}

// ---------------------------------------------------------------------------
// Kernel 2b: 64x64-tile GEMM for proj (N=768 -> 384 blocks).
// ---------------------------------------------------------------------------
__global__ __launch_bounds__(256) void gemm64_kernel(const unsigned short* __restrict__ A,
                                                     const unsigned short* __restrict__ Bt,
                                                     const float* __restrict__ bias,
                                                     float* __restrict__ C,
                                                     int M, int N, int K) {
    __shared__ __align__(16) unsigned short As[64 * 32];
    __shared__ __align__(16) unsigned short Bs[64 * 32];
    int t = threadIdx.x;
    int lane = t & 63, w = t >> 6;
    int wrow = w >> 1, wcol = w & 1;
    int quad = lane >> 4, l16 = lane & 15;
    int bm = blockIdx.y * 64, bn = blockIdx.x * 64;

    f32x4 acc[2][2];
#pragma unroll
    for (int i = 0; i < 2; i++)
#pragma unroll
        for (int j = 0; j < 2; j++)
            acc[i][j] = (f32x4){0.f, 0.f, 0.f, 0.f};

    int swz_s = ((lane >> 2) & 3) ^ ((lane >> 4) & 3);
    int gsel = ((lane & 3) ^ swz_s) * 8;
    const unsigned short* a0 = A  + (size_t)(bm + w * 16 + (lane >> 2)) * K + gsel;
    const unsigned short* b0 = Bt + (size_t)(bn + w * 16 + (lane >> 2)) * K + gsel;
    unsigned short* lA0 = &As[(w * 16) * 32];
    unsigned short* lB0 = &Bs[(w * 16) * 32];

    int swz_f = (l16 & 3) ^ ((l16 >> 2) & 3);
    int foff = (quad ^ swz_f) * 8;

    for (int k0 = 0; k0 < K; k0 += 32) {
        __syncthreads();
        gll16(a0 + k0, lA0);
        gll16(b0 + k0, lB0);
        __syncthreads();
        bf16x8 af[2], bfr[2];
#pragma unroll
        for (int mi = 0; mi < 2; mi++)
            af[mi] = *(const bf16x8*)&As[(wrow * 32 + mi * 16 + l16) * 32 + foff];
#pragma unroll
        for (int ni = 0; ni < 2; ni++)
            bfr[ni] = *(const bf16x8*)&Bs[(wcol * 32 + ni * 16 + l16) * 32 + foff];
#pragma unroll
        for (int mi = 0; mi < 2; mi++)
#pragma unroll
            for (int ni = 0; ni < 2; ni++)
                acc[mi][ni] = __builtin_amdgcn_mfma_f32_16x16x32_bf16(af[mi], bfr[ni], acc[mi][ni], 0, 0, 0);
    }

#pragma unroll
    for (int mi = 0; mi < 2; mi++) {
#pragma unroll
        for (int r = 0; r < 4; r++) {
            int row = bm + wrow * 32 + mi * 16 + quad * 4 + r;
#pragma unroll
            for (int ni = 0; ni < 2; ni++) {
                int col = bn + wcol * 32 + ni * 16 + l16;
                C[(size_t)row * N + col] = acc[mi][ni][r] + bias[col];
            }
        }
    }
}

// ---------------------------------------------------------------------------
// Kernel 3: gate: params = h1[BL,128] @ Wb2[128,60]; writes 1+gate, gate
// ---------------------------------------------------------------------------
__global__ __launch_bounds__(256) void gate_kernel(const float* __restrict__ h1,
                                                   const float* __restrict__ Wb2,
                                                   const float* __restrict__ temperature,
                                                   float* __restrict__ gate_ws,
                                                   float* __restrict__ gate_out) {
    __shared__ float w2s[RR * 60];
    __shared__ float h1s[4][RR];
    __shared__ float ps[4][60];
    int t = threadIdx.x;
    for (int i = t; i < RR * 60; i += 256) w2s[i] = Wb2[i];
    int rr = t >> 6, lane = t & 63;
    int row = blockIdx.x * 4 + rr;
    h1s[rr][lane]      = h1[(size_t)row * RR + lane];
    h1s[rr][64 + lane] = h1[(size_t)row * RR + 64 + lane];
    __syncthreads();
    if (lane < 60) {
        float acc = 0.f;
#pragma unroll 8
        for (int k = 0; k < RR; k++) acc += h1s[rr][k] * w2s[k * 60 + lane];
        ps[rr][lane] = acc;
    }
    __syncthreads();
    if (lane < HH) {
        float p0 = ps[rr][lane * 5 + 0];
        float p1 = ps[rr][lane * 5 + 1];
        float p2 = ps[rr][lane * 5 + 2];
        float p3 = ps[rr][lane * 5 + 3];
        float temp = fminf(fmaxf(temperature[0], 0.1f), 2.0f);
        float sa = sigmoidf_(p0);
        float sp = tanhf(p1) * PI_F;
        float ca = sigmoidf_(p2);
        float cp = tanhf(p3) * PI_F;
        float itf = tanhf(sa * ca * cosf(sp - cp)) * temp;
        float gt = sigmoidf_(itf);
        size_t gi = (size_t)row * HH + lane;
        gate_ws[gi] = 1.0f + gt;
        gate_out[gi] = gt;
    }
}

// ---------------------------------------------------------------------------
// Kernel 4 (pass A, split-fp16 MFMA, ~fp32-exact):
// S_c^T[e][d] = sum_j Vw[j][e] K[j][d] via 3-term hi/lo fp16 MFMA.
// z_c[d] = sum_j K[j][d] (fp32, during staging).
// states: st[e*64+d] = S^T, st[4096+d] = z.
// ---------------------------------------------------------------------------
__global__ __launch_bounds__(256) void passA_kernel(const float* __restrict__ qkv,
                                                    const float* __restrict__ gate_ws,
                                                    float* __restrict__ states) {
    int blk = blockIdx.x;
    int c = blk % NC, bh = blk / NC;
    int b = bh / HH, h = bh % HH;
    __shared__ __align__(16) unsigned short KTh[64 * SP], KTl[64 * SP];   // K^T[d][j]
    __shared__ __align__(16) unsigned short VTh[64 * SP], VTl[64 * SP];   // (V*w)^T[e][j]
    __shared__ float wsm[64];
    __shared__ float zpart[4][64];
    int t = threadIdx.x;
    size_t rowbase = (size_t)b * LL + c * CT;
    if (t < 64) wsm[t] = gate_ws[(rowbase + t) * HH + h];
    __syncthreads();
    {
        int d = t & 63, jg = t >> 6;    // wave jg covers j = jg*16 .. +15
        const float* kbase = &qkv[(rowbase + jg * 16) * D3 + DD + h * DH + d];
        const float* vbase = kbase + DD;
        float zl = 0.f;
#pragma unroll
        for (int s = 0; s < 8; s++) {
            int j = jg * 16 + 2 * s;
            float k0 = elu1f_(kbase[(2 * s) * D3]);
            float k1 = elu1f_(kbase[(2 * s + 1) * D3]);
            zl += k0 + k1;
            unsigned short h0, l0, h1v, l1;
            splith(k0, h0, l0); splith(k1, h1v, l1);
            *(int*)&KTh[d * SP + j] = (int)h0 | ((int)h1v << 16);
            *(int*)&KTl[d * SP + j] = (int)l0 | ((int)l1 << 16);
            float v0 = vbase[(2 * s) * D3] * wsm[j];
            float v1 = vbase[(2 * s + 1) * D3] * wsm[j + 1];
            splith(v0, h0, l0); splith(v1, h1v, l1);
            *(int*)&VTh[d * SP + j] = (int)h0 | ((int)h1v << 16);
            *(int*)&VTl[d * SP + j] = (int)l0 | ((int)l1 << 16);
        }
        zpart[jg][d] = zl;
    }
    __syncthreads();
    int lane = t & 63, w = t >> 6;
    int q = lane >> 4, l16 = lane & 15;
    float* st = states + (size_t)(bh * NC + c) * 4160;
    int vrow = (w * 16 + l16) * SP;
    const f16x8 vh0 = *(const f16x8*)&VTh[vrow + q * 8];
    const f16x8 vh1 = *(const f16x8*)&VTh[vrow + 32 + q * 8];
    const f16x8 vl0 = *(const f16x8*)&VTl[vrow + q * 8];
    const f16x8 vl1 = *(const f16x8*)&VTl[vrow + 32 + q * 8];
#pragma unroll
    for (int dt = 0; dt < 4; dt++) {
        int krow = (dt * 16 + l16) * SP;
        const f16x8 kh0 = *(const f16x8*)&KTh[krow + q * 8];
        const f16x8 kh1 = *(const f16x8*)&KTh[krow + 32 + q * 8];
        const f16x8 kl0 = *(const f16x8*)&KTl[krow + q * 8];
        const f16x8 kl1 = *(const f16x8*)&KTl[krow + 32 + q * 8];
        f32x4 a = (f32x4){0.f, 0.f, 0.f, 0.f};
        a = __builtin_amdgcn_mfma_f32_16x16x32_f16(vh0, kl0, a, 0, 0, 0);
        a = __builtin_amdgcn_mfma_f32_16x16x32_f16(vh1, kl1, a, 0, 0, 0);
        a = __builtin_amdgcn_mfma_f32_16x16x32_f16(vl0, kh0, a, 0, 0, 0);
        a = __builtin_amdgcn_mfma_f32_16x16x32_f16(vl1, kh1, a, 0, 0, 0);
        a = __builtin_amdgcn_mfma_f32_16x16x32_f16(vh0, kh0, a, 0, 0, 0);
        a = __builtin_amdgcn_mfma_f32_16x16x32_f16(vh1, kh1, a, 0, 0, 0);
#pragma unroll
        for (int r = 0; r < 4; r++)
            st[(w * 16 + q * 4 + r) * 64 + dt * 16 + l16] = a[r];
    }
    if (t < 64) st[4096 + t] = zpart[0][t] + zpart[1][t] + zpart[2][t] + zpart[3][t];
}

// ---------------------------------------------------------------------------
// Kernel 5 (pass C, split-fp16 MFMA + head-LN fused):
// scores = Q K^T (3-term split), causal mask + w-scale + fp32 den_intra,
// At (fp16 hi, separate array), num = Q S_prev^T (3-term) + At V^T (1-term);
// den_inter = fp32 Q.z; out = num/den -> head-LN -> bf16 store.
// ---------------------------------------------------------------------------
__global__ __launch_bounds__(256) void passC_kernel(const float* __restrict__ qkv,
                                                    const float* __restrict__ gate_ws,
                                                    const float* __restrict__ states,
                                                    const float* __restrict__ mg,
                                                    const float* __restrict__ mb,
                                                    unsigned short* __restrict__ attn_bf) {
    int blk = blockIdx.x;
    int c = blk % NC, bh = blk / NC;
    int b = bh / HH, h = bh % HH;
    __shared__ __align__(16) unsigned short Qh[64 * SP], Ql[64 * SP];  // Q[i][d]
    __shared__ __align__(16) unsigned short Kh[64 * SP], Kl[64 * SP];  // K[j][d]
    __shared__ __align__(16) unsigned short VT[64 * SP];               // V^T[e][j]
    __shared__ __align__(16) unsigned short Sh[64 * SP], Sl[64 * SP];  // S_prev^T[e][d]
    __shared__ __align__(16) unsigned short At[64 * SP];               // Atilde[i][j]
    __shared__ float wsm[64], zb[64], den1[64], den2[64], mgs[64], mbs[64];
    int t = threadIdx.x;
    size_t rowbase = (size_t)b * LL + c * CT;

    // ---- stage Q, K rows (elu, split fp16) ----
    {
        int j = t >> 2, f = t & 3;
        const float* qr = &qkv[(rowbase + j) * D3 + h * DH];
#pragma unroll
        for (int i2 = 0; i2 < 4; i2++) {
            int off = f * 16 + i2 * 4;
            float4 q4 = *(const float4*)&qr[off];
            ushort4 h4, l4;
            splith(elu1f_(q4.x), h4.x, l4.x); splith(elu1f_(q4.y), h4.y, l4.y);
            splith(elu1f_(q4.z), h4.z, l4.z); splith(elu1f_(q4.w), h4.w, l4.w);
            *(ushort4*)&Qh[j * SP + off] = h4;
            *(ushort4*)&Ql[j * SP + off] = l4;
            float4 k4 = *(const float4*)&qr[DD + off];
            splith(elu1f_(k4.x), h4.x, l4.x); splith(elu1f_(k4.y), h4.y, l4.y);
            splith(elu1f_(k4.z), h4.z, l4.z); splith(elu1f_(k4.w), h4.w, l4.w);
            *(ushort4*)&Kh[j * SP + off] = h4;
            *(ushort4*)&Kl[j * SP + off] = l4;
        }
    }
    // ---- stage V^T (fp16 hi only) ----
    {
        int e = t & 63, jg = t >> 6;
        const float* vbase = &qkv[(rowbase + jg * 16) * D3 + 2 * DD + h * DH + e];
#pragma unroll
        for (int s = 0; s < 8; s++) {
            int j = jg * 16 + 2 * s;
            float v0 = vbase[(2 * s) * D3];
            float v1 = vbase[(2 * s + 1) * D3];
            *(int*)&VT[e * SP + j] = packh2(v0, v1);
        }
    }
    // ---- stage S_prev^T = fp32 sum of chunk-local states -> split fp16 ----
    {
        int e = t >> 2, dbase = (t & 3) * 16;
        float acc[16];
#pragma unroll
        for (int i = 0; i < 16; i++) acc[i] = 0.f;
        for (int cp = 0; cp < c; cp++) {
            const float* st = states + (size_t)(bh * NC + cp) * 4160 + t * 16;
#pragma unroll
            for (int g2 = 0; g2 < 4; g2++) {
                float4 v4 = *(const float4*)&st[g2 * 4];
                acc[g2 * 4 + 0] += v4.x; acc[g2 * 4 + 1] += v4.y;
                acc[g2 * 4 + 2] += v4.z; acc[g2 * 4 + 3] += v4.w;
            }
        }
#pragma unroll
        for (int g2 = 0; g2 < 4; g2++) {
            ushort4 h4, l4;
            splith(acc[g2 * 4 + 0], h4.x, l4.x); splith(acc[g2 * 4 + 1], h4.y, l4.y);
            splith(acc[g2 * 4 + 2], h4.z, l4.z); splith(acc[g2 * 4 + 3], h4.w, l4.w);
            *(ushort4*)&Sh[e * SP + dbase + g2 * 4] = h4;
            *(ushort4*)&Sl[e * SP + dbase + g2 * 4] = l4;
        }
    }
    if (t < 64) {
        float z = 0.f;
        for (int cp = 0; cp < c; cp++)
            z += states[(size_t)(bh * NC + cp) * 4160 + 4096 + t];
        zb[t] = z;
        wsm[t] = gate_ws[(rowbase + t) * HH + h];
        mgs[t] = mg[t];
        mbs[t] = mb[t];
    }
    __syncthreads();

    int lane = t & 63, w = t >> 6;
    int q = lane >> 4, l16 = lane & 15;
    int qrow = (w * 16 + l16) * SP;
    const f16x8 qh0 = *(const f16x8*)&Qh[qrow + q * 8];
    const f16x8 qh1 = *(const f16x8*)&Qh[qrow + 32 + q * 8];
    const f16x8 ql0 = *(const f16x8*)&Ql[qrow + q * 8];
    const f16x8 ql1 = *(const f16x8*)&Ql[qrow + 32 + q * 8];

    // ---- scores = Q K^T (3-term split) ----
    f32x4 sa[4];
#pragma unroll
    for (int jt = 0; jt < 4; jt++) {
        int krow = (jt * 16 + l16) * SP;
        const f16x8 kh0 = *(const f16x8*)&Kh[krow + q * 8];
        const f16x8 kh1 = *(const f16x8*)&Kh[krow + 32 + q * 8];
        const f16x8 kl0 = *(const f16x8*)&Kl[krow + q * 8];
        const f16x8 kl1 = *(const f16x8*)&Kl[krow + 32 + q * 8];
        f32x4 a = (f32x4){0.f, 0.f, 0.f, 0.f};
        a = __builtin_amdgcn_mfma_f32_16x16x32_f16(qh0, kl0, a, 0, 0, 0);
        a = __builtin_amdgcn_mfma_f32_16x16x32_f16(qh1, kl1, a, 0, 0, 0);
        a = __builtin_amdgcn_mfma_f32_16x16x32_f16(ql0, kh0, a, 0, 0, 0);
        a = __builtin_amdgcn_mfma_f32_16x16x32_f16(ql1, kh1, a, 0, 0, 0);
        a = __builtin_amdgcn_mfma_f32_16x16x32_f16(qh0, kh0, a, 0, 0, 0);
        a = __builtin_amdgcn_mfma_f32_16x16x32_f16(qh1, kh1, a, 0, 0, 0);
        sa[jt] = a;
    }
    // ---- causal mask, w-scale, At (fp16), fp32 den_intra ----
    float den_p[4] = {0.f, 0.f, 0.f, 0.f};
#pragma unroll
    for (int jt = 0; jt < 4; jt++) {
        int j = jt * 16 + l16;
        float wj = wsm[j];
#pragma unroll
        for (int r = 0; r < 4; r++) {
            int i = w * 16 + q * 4 + r;
            float a = (j <= i) ? sa[jt][r] : 0.f;
            den_p[r] += a;
            At[i * SP + j] = f2h(a * wj);
        }
    }
#pragma unroll
    for (int r = 0; r < 4; r++) {
        den_p[r] += __shfl_xor(den_p[r], 1);
        den_p[r] += __shfl_xor(den_p[r], 2);
        den_p[r] += __shfl_xor(den_p[r], 4);
        den_p[r] += __shfl_xor(den_p[r], 8);
    }
    if (l16 == 0) {
#pragma unroll
        for (int r = 0; r < 4; r++) den1[w * 16 + q * 4 + r] = den_p[r];
    }
    // ---- den_inter = Q . z_prev (fp32) ----
    {
        int i2 = w * 16 + l16;
        float dp = 0.f;
#pragma unroll
        for (int s = 0; s < 16; s++) {
            float qv = h2f(Qh[i2 * SP + q * 16 + s]) + h2f(Ql[i2 * SP + q * 16 + s]);
            dp += qv * zb[q * 16 + s];
        }
        dp += __shfl_xor(dp, 16);
        dp += __shfl_xor(dp, 32);
        if (q == 0) den2[i2] = dp;
    }
    __syncthreads();   // At / den1 / den2 visible

    // ---- num = Q S_prev^T (3-term) + At V^T ----
    const f16x8 af0 = *(const f16x8*)&At[qrow + q * 8];
    const f16x8 af1 = *(const f16x8*)&At[qrow + 32 + q * 8];
    f32x4 nacc[4];
#pragma unroll
    for (int et = 0; et < 4; et++) {
        int erow = (et * 16 + l16) * SP;
        const f16x8 sh0 = *(const f16x8*)&Sh[erow + q * 8];
        const f16x8 sh1 = *(const f16x8*)&Sh[erow + 32 + q * 8];
        const f16x8 sl0 = *(const f16x8*)&Sl[erow + q * 8];
        const f16x8 sl1 = *(const f16x8*)&Sl[erow + 32 + q * 8];
        const f16x8 vf0 = *(const f16x8*)&VT[erow + q * 8];
        const f16x8 vf1 = *(const f16x8*)&VT[erow + 32 + q * 8];
        f32x4 a = (f32x4){0.f, 0.f, 0.f, 0.f};
        a = __builtin_amdgcn_mfma_f32_16x16x32_f16(qh0, sl0, a, 0, 0, 0);
        a = __builtin_amdgcn_mfma_f32_16x16x32_f16(qh1, sl1, a, 0, 0, 0);
        a = __builtin_amdgcn_mfma_f32_16x16x32_f16(ql0, sh0, a, 0, 0, 0);
        a = __builtin_amdgcn_mfma_f32_16x16x32_f16(ql1, sh1, a, 0, 0, 0);
        a = __builtin_amdgcn_mfma_f32_16x16x32_f16(qh0, sh0, a, 0, 0, 0);
        a = __builtin_amdgcn_mfma_f32_16x16x32_f16(qh1, sh1, a, 0, 0, 0);
        a = __builtin_amdgcn_mfma_f32_16x16x32_f16(af0, vf0, a, 0, 0, 0);
        a = __builtin_amdgcn_mfma_f32_16x16x32_f16(af1, vf1, a, 0, 0, 0);
        nacc[et] = a;
    }
    // ---- out = num/den, head-LN, bf16 store ----
#pragma unroll
    for (int r = 0; r < 4; r++) {
        int i = w * 16 + q * 4 + r;
        float inv = 1.0f / (den1[i] + den2[i] + 1e-6f);
        float o[4];
        float s = 0.f, s2 = 0.f;
#pragma unroll
        for (int et = 0; et < 4; et++) {
            float v = nacc[et][r] * inv;
            o[et] = v;
            s += v;
            s2 += v * v;
        }
        s  += __shfl_xor(s, 1);  s  += __shfl_xor(s, 2);
        s  += __shfl_xor(s, 4);  s  += __shfl_xor(s, 8);
        s2 += __shfl_xor(s2, 1); s2 += __shfl_xor(s2, 2);
        s2 += __shfl_xor(s2, 4); s2 += __shfl_xor(s2, 8);
        float mu = s * (1.0f / DH);
        float var = s2 * (1.0f / DH) - mu * mu;
        float rstd = rsqrtf(var + 1e-5f);
        size_t gb = (rowbase + i) * DD + h * DH;
#pragma unroll
        for (int et = 0; et < 4; et++) {
            int e = et * 16 + l16;
            attn_bf[gb + e] = f2bf((o[et] - mu) * rstd * mgs[e] + mbs[e]);
        }
    }
}

// ---------------------------------------------------------------------------
extern "C" void kernel_launch(void* const* d_in, const int* in_sizes, int n_in,
                              void* d_out, int out_size, void* d_ws, size_t ws_size,
                              hipStream_t stream) {
    const float* x    = (const float*)d_in[0];
    const float* Wqkv = (const float*)d_in[1];
    const float* bqkv = (const float*)d_in[2];
    const float* Wb1  = (const float*)d_in[3];
    const float* Wb2  = (const float*)d_in[4];
    const float* temperature = (const float*)d_in[5];
    const float* Wproj = (const float*)d_in[6];
    const float* bproj = (const float*)d_in[7];
    const float* ln_g = (const float*)d_in[8];
    const float* ln_b = (const float*)d_in[9];
    const float* mn_g = (const float*)d_in[10];
    const float* mn_b = (const float*)d_in[11];

    float* out0     = (float*)d_out;                    // (B,L,D)
    float* gate_out = out0 + (size_t)BL * DD;           // (B,L,H)

    float* ws = (float*)d_ws;
    float* qkv    = ws;                                   // 4,718,592 f32
    float* h1     = qkv + (size_t)BL * D3;                //   262,144
    float* gate   = h1 + (size_t)BL * RR;                 //    24,576 (holds 1+g)
    float* states = gate + (size_t)BL * HH;               // 1,597,440
    unsigned short* xnbf  = (unsigned short*)(states + (size_t)BB * HH * NC * 4160);
    unsigned short* xbf    = xnbf + (size_t)BL * DD;
    unsigned short* attnbf = xbf + (size_t)BL * DD;
    unsigned short* wqkvt  = attnbf + (size_t)BL * DD;
    unsigned short* wb1t   = wqkvt + (size_t)D3 * DD;
    unsigned short* wprojt = wb1t + (size_t)DD * RR;

    // 1. LN + x->bf16 + all weight transposes
    prep_kernel<<<4448, 256, 0, stream>>>(x, ln_g, ln_b, xnbf, xbf,
                                          Wqkv, Wb1, Wproj, wqkvt, wb1t, wprojt);
    // 2. qkv GEMM + Wb1 GEMM fused
    gemm_big_kernel<<<304, 256, 0, stream>>>(xnbf, wqkvt, bqkv, qkv, xbf, wb1t, h1);
    // 3. gate
    gate_kernel<<<BL / 4, 256, 0, stream>>>(h1, Wb2, temperature, gate, gate_out);
    // 4. chunk-local states (split-fp16 MFMA, 384 blocks)
    passA_kernel<<<BB * HH * NC, 256, 0, stream>>>(qkv, gate, states);
    // 5. replay (split-fp16 MFMA) + inline prefix + head-LN -> bf16 (384 blocks)
    passC_kernel<<<BB * HH * NC, 256, 0, stream>>>(qkv, gate, states, mn_g, mn_b, attnbf);
    // 6. out = attn @ Wproj + bproj
    gemm64_kernel<<<dim3(DD / 64, BL / 64), 256, 0, stream>>>(attnbf, wprojt, bproj, out0, BL, DD, DD);
}

// Round 9
// 152.622 us; speedup vs baseline: 1.5362x; 1.0109x over previous
//
#include <hip/hip_runtime.h>
#include <hip/hip_bf16.h>
#include <math.h>

// Problem constants
#define BB 4
#define LL 512
#define DD 768
#define HH 12
#define DH 64
#define RR 128
#define BL (BB*LL)      // 2048
#define D3 (3*DD)       // 2304
#define NC 8            // chunks over L
#define CT 64           // chunk length
#define SP 72           // LDS row stride (elems), 144 B, 16B-aligned rows
#define PI_F 3.14159265358979323846f

typedef short bf16x8 __attribute__((ext_vector_type(8)));
typedef _Float16 f16x8 __attribute__((ext_vector_type(8)));
typedef float f32x4 __attribute__((ext_vector_type(4)));

__device__ __forceinline__ float sigmoidf_(float x) { return 1.0f / (1.0f + expf(-x)); }
__device__ __forceinline__ float elu1f_(float x)    { return x > 0.0f ? x + 1.0f : expf(x); }
__device__ __forceinline__ unsigned short f2bf(float f) {
    unsigned u = __float_as_uint(f);
    unsigned r = u + 0x7FFF + ((u >> 16) & 1);
    return (unsigned short)(r >> 16);
}
// fp16 convert (RNE) + helpers
__device__ __forceinline__ unsigned short f2h(float f) {
    _Float16 h = (_Float16)f;
    return *(unsigned short*)&h;
}
__device__ __forceinline__ float h2f(unsigned short u) {
    _Float16 h = *(_Float16*)&u;
    return (float)h;
}
__device__ __forceinline__ int packh2(float lo, float hi) {
    return (int)f2h(lo) | ((int)f2h(hi) << 16);
}
// split fp32 -> fp16 hi + fp16 lo residual
__device__ __forceinline__ void splith(float v, unsigned short& h, unsigned short& l) {
    h = f2h(v);
    l = f2h(v - h2f(h));
}
// async global->LDS DMA, 16 B per lane
__device__ __forceinline__ void gll16(const void* g, void* l) {
    __builtin_amdgcn_global_load_lds(
        (const __attribute__((address_space(1))) void*)g,
        (__attribute__((address_space(3))) void*)l, 16, 0, 0);
}

// In-block gate computation for 64 rows of head h.
// w2h: LDS float[512] scratch; wsm: LDS float[64] out (1+gate).
// WRITE_GATE: also store gate to gate_out.
template <bool WRITE_GATE>
__device__ __forceinline__ void compute_gate_block(int t, int h, size_t rowbase,
                                                   const float* __restrict__ h1,
                                                   const float* __restrict__ Wb2,
                                                   const float* __restrict__ temperature,
                                                   float* __restrict__ w2h,
                                                   float* __restrict__ wsm,
                                                   float* __restrict__ gate_out) {
    // stage Wb2 head window: w2h[kk*4+k] = Wb2[kk*60 + h*5 + k], kk<128, k<4
    for (int i = t; i < 512; i += 256)
        w2h[i] = Wb2[(i >> 2) * 60 + h * 5 + (i & 3)];
    __syncthreads();
    int row = t >> 2, part = t & 3;
    const float* h1r = &h1[(rowbase + row) * RR + part * 32];
    float p0 = 0.f, p1 = 0.f, p2 = 0.f, p3 = 0.f;
#pragma unroll 8
    for (int kk = 0; kk < 32; kk++) {
        float hv = h1r[kk];
        const float* wp = &w2h[(part * 32 + kk) * 4];
        p0 += hv * wp[0];
        p1 += hv * wp[1];
        p2 += hv * wp[2];
        p3 += hv * wp[3];
    }
    p0 += __shfl_xor(p0, 1); p0 += __shfl_xor(p0, 2);
    p1 += __shfl_xor(p1, 1); p1 += __shfl_xor(p1, 2);
    p2 += __shfl_xor(p2, 1); p2 += __shfl_xor(p2, 2);
    p3 += __shfl_xor(p3, 1); p3 += __shfl_xor(p3, 2);
    if (part == 0) {
        float temp = fminf(fmaxf(temperature[0], 0.1f), 2.0f);
        float sa = sigmoidf_(p0);
        float sp = tanhf(p1) * PI_F;
        float ca = sigmoidf_(p2);
        float cp = tanhf(p3) * PI_F;
        float itf = tanhf(sa * ca * cosf(sp - cp)) * temp;
        float gt = sigmoidf_(itf);
        wsm[row] = 1.0f + gt;
        if (WRITE_GATE) gate_out[(rowbase + row) * HH + h] = gt;
    }
    __syncthreads();
}

// ---------------------------------------------------------------------------
// Kernel 1 (prep, fused): bid<2048 -> row-LN of x (bf16) + raw x (bf16);
// bid>=2048 -> weight transposes f32 [K][N] -> bf16 [N][K].
// ---------------------------------------------------------------------------
__global__ __launch_bounds__(256) void prep_kernel(const float* __restrict__ x,
                                                   const float* __restrict__ g,
                                                   const float* __restrict__ b,
                                                   unsigned short* __restrict__ xn,
                                                   unsigned short* __restrict__ xb,
                                                   const float* __restrict__ Wqkv,
                                                   const float* __restrict__ Wb1,
                                                   const float* __restrict__ Wproj,
                                                   unsigned short* __restrict__ wqkvt,
                                                   unsigned short* __restrict__ wb1t,
                                                   unsigned short* __restrict__ wprojt) {
    __shared__ float smem[32 * 33];
    int bid = blockIdx.x;
    int t = threadIdx.x;
    if (bid < 2048) {
        int row = bid;
        int w = t >> 6, lane = t & 63;
        float v[3];
        float s = 0.f, s2 = 0.f;
#pragma unroll
        for (int i = 0; i < 3; i++) {
            v[i] = x[(size_t)row * DD + t + i * 256];
            s += v[i];
            s2 += v[i] * v[i];
        }
#pragma unroll
        for (int off = 1; off < 64; off <<= 1) {
            s  += __shfl_xor(s, off);
            s2 += __shfl_xor(s2, off);
        }
        if (lane == 0) { smem[w] = s; smem[4 + w] = s2; }
        __syncthreads();
        s  = smem[0] + smem[1] + smem[2] + smem[3];
        s2 = smem[4] + smem[5] + smem[6] + smem[7];
        float mu = s * (1.0f / DD);
        float var = s2 * (1.0f / DD) - mu * mu;
        float rstd = rsqrtf(var + 1e-5f);
#pragma unroll
        for (int i = 0; i < 3; i++) {
            int col = t + i * 256;
            xn[(size_t)row * DD + col] = f2bf((v[i] - mu) * rstd * g[col] + b[col]);
            xb[(size_t)row * DD + col] = f2bf(v[i]);
        }
    } else {
        bid -= 2048;
        const float* in; unsigned short* out; int K, N, bx, by;
        if (bid < 1728)      { in = Wqkv;  out = wqkvt;  K = DD; N = D3; bx = bid % 72; by = bid / 72; }
        else if (bid < 1824) { bid -= 1728; in = Wb1;  out = wb1t;  K = DD; N = RR; bx = bid % 4;  by = bid / 4; }
        else                 { bid -= 1824; in = Wproj; out = wprojt; K = DD; N = DD; bx = bid % 24; by = bid / 24; }
        int n0 = bx * 32, k0 = by * 32;
        int tx = t & 31, ty = t >> 5;
        float (*tile)[33] = (float(*)[33])smem;
#pragma unroll
        for (int i = 0; i < 4; i++)
            tile[ty + i * 8][tx] = in[(size_t)(k0 + ty + i * 8) * N + n0 + tx];
        __syncthreads();
#pragma unroll
        for (int i = 0; i < 4; i++)
            out[(size_t)(n0 + ty + i * 8) * K + k0 + tx] = f2bf(tile[tx][ty + i * 8]);
    }
}

// ---------------------------------------------------------------------------
// Kernel 2 (fused QKV + Wb1 GEMM): 128x128 tile, gll16 staging, XOR-swizzled
// unpadded LDS. Blocks 0..287: qkv. Blocks 288..303: h1 = silu(xb @ Wb1).
// ---------------------------------------------------------------------------
__global__ __launch_bounds__(256) void gemm_big_kernel(const unsigned short* __restrict__ xn,
                                                       const unsigned short* __restrict__ wqkvt,
                                                       const float* __restrict__ bqkv,
                                                       float* __restrict__ qkv,
                                                       const unsigned short* __restrict__ xb,
                                                       const unsigned short* __restrict__ wb1t,
                                                       float* __restrict__ h1) {
    __shared__ __align__(16) unsigned short As[128 * 32];
    __shared__ __align__(16) unsigned short Bs[128 * 32];
    int bid = blockIdx.x;
    const unsigned short *A, *Bt;
    const float* bias;
    float* C;
    int N, act, bm, bn;
    if (bid < 288) { A = xn; Bt = wqkvt; bias = bqkv; C = qkv; N = D3; act = 0;
                     bn = (bid % 18) * 128; bm = (bid / 18) * 128; }
    else           { int b2 = bid - 288; A = xb; Bt = wb1t; bias = nullptr; C = h1; N = RR; act = 1;
                     bm = b2 * 128; bn = 0; }
    const int K = DD;

    int t = threadIdx.x;
    int lane = t & 63, w = t >> 6;
    int wrow = w >> 1, wcol = w & 1;
    int quad = lane >> 4, l16 = lane & 15;

    f32x4 acc[4][4];
#pragma unroll
    for (int i = 0; i < 4; i++)
#pragma unroll
        for (int j = 0; j < 4; j++)
            acc[i][j] = (f32x4){0.f, 0.f, 0.f, 0.f};

    int swz_s = ((lane >> 2) & 3) ^ ((lane >> 4) & 3);
    int gsel = ((lane & 3) ^ swz_s) * 8;
    const unsigned short* a0 = A  + (size_t)(bm + w * 16 + (lane >> 2)) * K + gsel;
    const unsigned short* a1 = a0 + (size_t)64 * K;
    const unsigned short* b0 = Bt + (size_t)(bn + w * 16 + (lane >> 2)) * K + gsel;
    const unsigned short* b1 = b0 + (size_t)64 * K;
    unsigned short* lA0 = &As[(w * 16) * 32];
    unsigned short* lA1 = &As[(64 + w * 16) * 32];
    unsigned short* lB0 = &Bs[(w * 16) * 32];
    unsigned short* lB1 = &Bs[(64 + w * 16) * 32];

    int swz_f = (l16 & 3) ^ ((l16 >> 2) & 3);
    int foff = (quad ^ swz_f) * 8;

    for (int k0 = 0; k0 < K; k0 += 32) {
        __syncthreads();
        gll16(a0 + k0, lA0);
        gll16(a1 + k0, lA1);
        gll16(b0 + k0, lB0);
        gll16(b1 + k0, lB1);
        __syncthreads();
        bf16x8 af[4], bfr[4];
#pragma unroll
        for (int mi = 0; mi < 4; mi++)
            af[mi] = *(const bf16x8*)&As[(wrow * 64 + mi * 16 + l16) * 32 + foff];
#pragma unroll
        for (int ni = 0; ni < 4; ni++)
            bfr[ni] = *(const bf16x8*)&Bs[(wcol * 64 + ni * 16 + l16) * 32 + foff];
#pragma unroll
        for (int mi = 0; mi < 4; mi++)
#pragma unroll
            for (int ni = 0; ni < 4; ni++)
                acc[mi][ni] = __builtin_amdgcn_mfma_f32_16x16x32_bf16(af[mi], bfr[ni], acc[mi][ni], 0, 0, 0);
    }

#pragma unroll
    for (int mi = 0; mi < 4; mi++) {
#pragma unroll
        for (int r = 0; r < 4; r++) {
            int row = bm + wrow * 64 + mi * 16 + quad * 4 + r;
#pragma unroll
            for (int ni = 0; ni < 4; ni++) {
                int col = bn + wcol * 64 + ni * 16 + l16;
                float v = acc[mi][ni][r];
                if (act == 0) v += bias[col];
                else          v = v * sigmoidf_(v);
                C[(size_t)row * N + col] = v;
            }
        }
    }
}

// ---------------------------------------------------------------------------
// Kernel 2b: 64x64-tile GEMM for proj (N=768 -> 384 blocks).
// ---------------------------------------------------------------------------
__global__ __launch_bounds__(256) void gemm64_kernel(const unsigned short* __restrict__ A,
                                                     const unsigned short* __restrict__ Bt,
                                                     const float* __restrict__ bias,
                                                     float* __restrict__ C,
                                                     int M, int N, int K) {
    __shared__ __align__(16) unsigned short As[64 * 32];
    __shared__ __align__(16) unsigned short Bs[64 * 32];
    int t = threadIdx.x;
    int lane = t & 63, w = t >> 6;
    int wrow = w >> 1, wcol = w & 1;
    int quad = lane >> 4, l16 = lane & 15;
    int bm = blockIdx.y * 64, bn = blockIdx.x * 64;

    f32x4 acc[2][2];
#pragma unroll
    for (int i = 0; i < 2; i++)
#pragma unroll
        for (int j = 0; j < 2; j++)
            acc[i][j] = (f32x4){0.f, 0.f, 0.f, 0.f};

    int swz_s = ((lane >> 2) & 3) ^ ((lane >> 4) & 3);
    int gsel = ((lane & 3) ^ swz_s) * 8;
    const unsigned short* a0 = A  + (size_t)(bm + w * 16 + (lane >> 2)) * K + gsel;
    const unsigned short* b0 = Bt + (size_t)(bn + w * 16 + (lane >> 2)) * K + gsel;
    unsigned short* lA0 = &As[(w * 16) * 32];
    unsigned short* lB0 = &Bs[(w * 16) * 32];

    int swz_f = (l16 & 3) ^ ((l16 >> 2) & 3);
    int foff = (quad ^ swz_f) * 8;

    for (int k0 = 0; k0 < K; k0 += 32) {
        __syncthreads();
        gll16(a0 + k0, lA0);
        gll16(b0 + k0, lB0);
        __syncthreads();
        bf16x8 af[2], bfr[2];
#pragma unroll
        for (int mi = 0; mi < 2; mi++)
            af[mi] = *(const bf16x8*)&As[(wrow * 32 + mi * 16 + l16) * 32 + foff];
#pragma unroll
        for (int ni = 0; ni < 2; ni++)
            bfr[ni] = *(const bf16x8*)&Bs[(wcol * 32 + ni * 16 + l16) * 32 + foff];
#pragma unroll
        for (int mi = 0; mi < 2; mi++)
#pragma unroll
            for (int ni = 0; ni < 2; ni++)
                acc[mi][ni] = __builtin_amdgcn_mfma_f32_16x16x32_bf16(af[mi], bfr[ni], acc[mi][ni], 0, 0, 0);
    }

#pragma unroll
    for (int mi = 0; mi < 2; mi++) {
#pragma unroll
        for (int r = 0; r < 4; r++) {
            int row = bm + wrow * 32 + mi * 16 + quad * 4 + r;
#pragma unroll
            for (int ni = 0; ni < 2; ni++) {
                int col = bn + wcol * 32 + ni * 16 + l16;
                C[(size_t)row * N + col] = acc[mi][ni][r] + bias[col];
            }
        }
    }
}

// ---------------------------------------------------------------------------
// Kernel 4 (pass A, split-fp16 MFMA + in-block gate):
// gate for this chunk's 64 rows computed in-block (writes gate_out), then
// S_c^T[e][d] = sum_j Vw[j][e] K[j][d] via 3-term hi/lo fp16 MFMA.
// z_c[d] = sum_j K[j][d] (fp32, during staging).
// states: st[e*64+d] = S^T, st[4096+d] = z.
// ---------------------------------------------------------------------------
__global__ __launch_bounds__(256) void passA_kernel(const float* __restrict__ qkv,
                                                    const float* __restrict__ h1,
                                                    const float* __restrict__ Wb2,
                                                    const float* __restrict__ temperature,
                                                    float* __restrict__ gate_out,
                                                    float* __restrict__ states) {
    int blk = blockIdx.x;
    int c = blk % NC, bh = blk / NC;
    int b = bh / HH, h = bh % HH;
    __shared__ __align__(16) unsigned short KTh[64 * SP], KTl[64 * SP];   // K^T[d][j]
    __shared__ __align__(16) unsigned short VTh[64 * SP], VTl[64 * SP];   // (V*w)^T[e][j]
    __shared__ float wsm[64];
    __shared__ float zpart[4][64];
    __shared__ float w2h[512];
    int t = threadIdx.x;
    size_t rowbase = (size_t)b * LL + c * CT;

    // ---- in-block gate (writes wsm = 1+g, gate_out) ----
    compute_gate_block<true>(t, h, rowbase, h1, Wb2, temperature, w2h, wsm, gate_out);

    {
        int d = t & 63, jg = t >> 6;    // wave jg covers j = jg*16 .. +15
        const float* kbase = &qkv[(rowbase + jg * 16) * D3 + DD + h * DH + d];
        const float* vbase = kbase + DD;
        float zl = 0.f;
#pragma unroll
        for (int s = 0; s < 8; s++) {
            int j = jg * 16 + 2 * s;
            float k0 = elu1f_(kbase[(2 * s) * D3]);
            float k1 = elu1f_(kbase[(2 * s + 1) * D3]);
            zl += k0 + k1;
            unsigned short h0, l0, h1v, l1;
            splith(k0, h0, l0); splith(k1, h1v, l1);
            *(int*)&KTh[d * SP + j] = (int)h0 | ((int)h1v << 16);
            *(int*)&KTl[d * SP + j] = (int)l0 | ((int)l1 << 16);
            float v0 = vbase[(2 * s) * D3] * wsm[j];
            float v1 = vbase[(2 * s + 1) * D3] * wsm[j + 1];
            splith(v0, h0, l0); splith(v1, h1v, l1);
            *(int*)&VTh[d * SP + j] = (int)h0 | ((int)h1v << 16);
            *(int*)&VTl[d * SP + j] = (int)l0 | ((int)l1 << 16);
        }
        zpart[jg][d] = zl;
    }
    __syncthreads();
    int lane = t & 63, w = t >> 6;
    int q = lane >> 4, l16 = lane & 15;
    float* st = states + (size_t)(bh * NC + c) * 4160;
    int vrow = (w * 16 + l16) * SP;
    const f16x8 vh0 = *(const f16x8*)&VTh[vrow + q * 8];
    const f16x8 vh1 = *(const f16x8*)&VTh[vrow + 32 + q * 8];
    const f16x8 vl0 = *(const f16x8*)&VTl[vrow + q * 8];
    const f16x8 vl1 = *(const f16x8*)&VTl[vrow + 32 + q * 8];
#pragma unroll
    for (int dt = 0; dt < 4; dt++) {
        int krow = (dt * 16 + l16) * SP;
        const f16x8 kh0 = *(const f16x8*)&KTh[krow + q * 8];
        const f16x8 kh1 = *(const f16x8*)&KTh[krow + 32 + q * 8];
        const f16x8 kl0 = *(const f16x8*)&KTl[krow + q * 8];
        const f16x8 kl1 = *(const f16x8*)&KTl[krow + 32 + q * 8];
        f32x4 a = (f32x4){0.f, 0.f, 0.f, 0.f};
        a = __builtin_amdgcn_mfma_f32_16x16x32_f16(vh0, kl0, a, 0, 0, 0);
        a = __builtin_amdgcn_mfma_f32_16x16x32_f16(vh1, kl1, a, 0, 0, 0);
        a = __builtin_amdgcn_mfma_f32_16x16x32_f16(vl0, kh0, a, 0, 0, 0);
        a = __builtin_amdgcn_mfma_f32_16x16x32_f16(vl1, kh1, a, 0, 0, 0);
        a = __builtin_amdgcn_mfma_f32_16x16x32_f16(vh0, kh0, a, 0, 0, 0);
        a = __builtin_amdgcn_mfma_f32_16x16x32_f16(vh1, kh1, a, 0, 0, 0);
#pragma unroll
        for (int r = 0; r < 4; r++)
            st[(w * 16 + q * 4 + r) * 64 + dt * 16 + l16] = a[r];
    }
    if (t < 64) st[4096 + t] = zpart[0][t] + zpart[1][t] + zpart[2][t] + zpart[3][t];
}

// ---------------------------------------------------------------------------
// Kernel 5 (pass C, split-fp16 MFMA + in-block gate + head-LN fused):
// gate recomputed in-block (identical fp32 path, no gate_out write),
// scores = Q K^T (3-term split), causal mask + w-scale + fp32 den_intra,
// At (fp16 hi), num = Q S_prev^T (3-term) + At V^T; den_inter = fp32 Q.z;
// out = num/den -> head-LN -> bf16 store.
// ---------------------------------------------------------------------------
__global__ __launch_bounds__(256) void passC_kernel(const float* __restrict__ qkv,
                                                    const float* __restrict__ h1,
                                                    const float* __restrict__ Wb2,
                                                    const float* __restrict__ temperature,
                                                    const float* __restrict__ states,
                                                    const float* __restrict__ mg,
                                                    const float* __restrict__ mb,
                                                    unsigned short* __restrict__ attn_bf) {
    int blk = blockIdx.x;
    int c = blk % NC, bh = blk / NC;
    int b = bh / HH, h = bh % HH;
    __shared__ __align__(16) unsigned short Qh[64 * SP], Ql[64 * SP];  // Q[i][d]
    __shared__ __align__(16) unsigned short Kh[64 * SP], Kl[64 * SP];  // K[j][d]
    __shared__ __align__(16) unsigned short VT[64 * SP];               // V^T[e][j]
    __shared__ __align__(16) unsigned short Sh[64 * SP], Sl[64 * SP];  // S_prev^T[e][d]
    __shared__ __align__(16) unsigned short At[64 * SP];               // Atilde[i][j]
    __shared__ float wsm[64], zb[64], den1[64], den2[64], mgs[64], mbs[64];
    __shared__ float w2h[512];
    int t = threadIdx.x;
    size_t rowbase = (size_t)b * LL + c * CT;

    // ---- in-block gate (wsm = 1+g) ----
    compute_gate_block<false>(t, h, rowbase, h1, Wb2, temperature, w2h, wsm, nullptr);

    // ---- stage Q, K rows (elu, split fp16) ----
    {
        int j = t >> 2, f = t & 3;
        const float* qr = &qkv[(rowbase + j) * D3 + h * DH];
#pragma unroll
        for (int i2 = 0; i2 < 4; i2++) {
            int off = f * 16 + i2 * 4;
            float4 q4 = *(const float4*)&qr[off];
            ushort4 h4, l4;
            splith(elu1f_(q4.x), h4.x, l4.x); splith(elu1f_(q4.y), h4.y, l4.y);
            splith(elu1f_(q4.z), h4.z, l4.z); splith(elu1f_(q4.w), h4.w, l4.w);
            *(ushort4*)&Qh[j * SP + off] = h4;
            *(ushort4*)&Ql[j * SP + off] = l4;
            float4 k4 = *(const float4*)&qr[DD + off];
            splith(elu1f_(k4.x), h4.x, l4.x); splith(elu1f_(k4.y), h4.y, l4.y);
            splith(elu1f_(k4.z), h4.z, l4.z); splith(elu1f_(k4.w), h4.w, l4.w);
            *(ushort4*)&Kh[j * SP + off] = h4;
            *(ushort4*)&Kl[j * SP + off] = l4;
        }
    }
    // ---- stage V^T (fp16 hi only) ----
    {
        int e = t & 63, jg = t >> 6;
        const float* vbase = &qkv[(rowbase + jg * 16) * D3 + 2 * DD + h * DH + e];
#pragma unroll
        for (int s = 0; s < 8; s++) {
            int j = jg * 16 + 2 * s;
            float v0 = vbase[(2 * s) * D3];
            float v1 = vbase[(2 * s + 1) * D3];
            *(int*)&VT[e * SP + j] = packh2(v0, v1);
        }
    }
    // ---- stage S_prev^T = fp32 sum of chunk-local states -> split fp16 ----
    {
        int e = t >> 2, dbase = (t & 3) * 16;
        float acc[16];
#pragma unroll
        for (int i = 0; i < 16; i++) acc[i] = 0.f;
        for (int cp = 0; cp < c; cp++) {
            const float* st = states + (size_t)(bh * NC + cp) * 4160 + t * 16;
#pragma unroll
            for (int g2 = 0; g2 < 4; g2++) {
                float4 v4 = *(const float4*)&st[g2 * 4];
                acc[g2 * 4 + 0] += v4.x; acc[g2 * 4 + 1] += v4.y;
                acc[g2 * 4 + 2] += v4.z; acc[g2 * 4 + 3] += v4.w;
            }
        }
#pragma unroll
        for (int g2 = 0; g2 < 4; g2++) {
            ushort4 h4, l4;
            splith(acc[g2 * 4 + 0], h4.x, l4.x); splith(acc[g2 * 4 + 1], h4.y, l4.y);
            splith(acc[g2 * 4 + 2], h4.z, l4.z); splith(acc[g2 * 4 + 3], h4.w, l4.w);
            *(ushort4*)&Sh[e * SP + dbase + g2 * 4] = h4;
            *(ushort4*)&Sl[e * SP + dbase + g2 * 4] = l4;
        }
    }
    if (t < 64) {
        float z = 0.f;
        for (int cp = 0; cp < c; cp++)
            z += states[(size_t)(bh * NC + cp) * 4160 + 4096 + t];
        zb[t] = z;
        mgs[t] = mg[t];
        mbs[t] = mb[t];
    }
    __syncthreads();

    int lane = t & 63, w = t >> 6;
    int q = lane >> 4, l16 = lane & 15;
    int qrow = (w * 16 + l16) * SP;
    const f16x8 qh0 = *(const f16x8*)&Qh[qrow + q * 8];
    const f16x8 qh1 = *(const f16x8*)&Qh[qrow + 32 + q * 8];
    const f16x8 ql0 = *(const f16x8*)&Ql[qrow + q * 8];
    const f16x8 ql1 = *(const f16x8*)&Ql[qrow + 32 + q * 8];

    // ---- scores = Q K^T (3-term split) ----
    f32x4 sa[4];
#pragma unroll
    for (int jt = 0; jt < 4; jt++) {
        int krow = (jt * 16 + l16) * SP;
        const f16x8 kh0 = *(const f16x8*)&Kh[krow + q * 8];
        const f16x8 kh1 = *(const f16x8*)&Kh[krow + 32 + q * 8];
        const f16x8 kl0 = *(const f16x8*)&Kl[krow + q * 8];
        const f16x8 kl1 = *(const f16x8*)&Kl[krow + 32 + q * 8];
        f32x4 a = (f32x4){0.f, 0.f, 0.f, 0.f};
        a = __builtin_amdgcn_mfma_f32_16x16x32_f16(qh0, kl0, a, 0, 0, 0);
        a = __builtin_amdgcn_mfma_f32_16x16x32_f16(qh1, kl1, a, 0, 0, 0);
        a = __builtin_amdgcn_mfma_f32_16x16x32_f16(ql0, kh0, a, 0, 0, 0);
        a = __builtin_amdgcn_mfma_f32_16x16x32_f16(ql1, kh1, a, 0, 0, 0);
        a = __builtin_amdgcn_mfma_f32_16x16x32_f16(qh0, kh0, a, 0, 0, 0);
        a = __builtin_amdgcn_mfma_f32_16x16x32_f16(qh1, kh1, a, 0, 0, 0);
        sa[jt] = a;
    }
    // ---- causal mask, w-scale, At (fp16), fp32 den_intra ----
    float den_p[4] = {0.f, 0.f, 0.f, 0.f};
#pragma unroll
    for (int jt = 0; jt < 4; jt++) {
        int j = jt * 16 + l16;
        float wj = wsm[j];
#pragma unroll
        for (int r = 0; r < 4; r++) {
            int i = w * 16 + q * 4 + r;
            float a = (j <= i) ? sa[jt][r] : 0.f;
            den_p[r] += a;
            At[i * SP + j] = f2h(a * wj);
        }
    }
#pragma unroll
    for (int r = 0; r < 4; r++) {
        den_p[r] += __shfl_xor(den_p[r], 1);
        den_p[r] += __shfl_xor(den_p[r], 2);
        den_p[r] += __shfl_xor(den_p[r], 4);
        den_p[r] += __shfl_xor(den_p[r], 8);
    }
    if (l16 == 0) {
#pragma unroll
        for (int r = 0; r < 4; r++) den1[w * 16 + q * 4 + r] = den_p[r];
    }
    // ---- den_inter = Q . z_prev (fp32) ----
    {
        int i2 = w * 16 + l16;
        float dp = 0.f;
#pragma unroll
        for (int s = 0; s < 16; s++) {
            float qv = h2f(Qh[i2 * SP + q * 16 + s]) + h2f(Ql[i2 * SP + q * 16 + s]);
            dp += qv * zb[q * 16 + s];
        }
        dp += __shfl_xor(dp, 16);
        dp += __shfl_xor(dp, 32);
        if (q == 0) den2[i2] = dp;
    }
    __syncthreads();   // At / den1 / den2 visible

    // ---- num = Q S_prev^T (3-term) + At V^T ----
    const f16x8 af0 = *(const f16x8*)&At[qrow + q * 8];
    const f16x8 af1 = *(const f16x8*)&At[qrow + 32 + q * 8];
    f32x4 nacc[4];
#pragma unroll
    for (int et = 0; et < 4; et++) {
        int erow = (et * 16 + l16) * SP;
        const f16x8 sh0 = *(const f16x8*)&Sh[erow + q * 8];
        const f16x8 sh1 = *(const f16x8*)&Sh[erow + 32 + q * 8];
        const f16x8 sl0 = *(const f16x8*)&Sl[erow + q * 8];
        const f16x8 sl1 = *(const f16x8*)&Sl[erow + 32 + q * 8];
        const f16x8 vf0 = *(const f16x8*)&VT[erow + q * 8];
        const f16x8 vf1 = *(const f16x8*)&VT[erow + 32 + q * 8];
        f32x4 a = (f32x4){0.f, 0.f, 0.f, 0.f};
        a = __builtin_amdgcn_mfma_f32_16x16x32_f16(qh0, sl0, a, 0, 0, 0);
        a = __builtin_amdgcn_mfma_f32_16x16x32_f16(qh1, sl1, a, 0, 0, 0);
        a = __builtin_amdgcn_mfma_f32_16x16x32_f16(ql0, sh0, a, 0, 0, 0);
        a = __builtin_amdgcn_mfma_f32_16x16x32_f16(ql1, sh1, a, 0, 0, 0);
        a = __builtin_amdgcn_mfma_f32_16x16x32_f16(qh0, sh0, a, 0, 0, 0);
        a = __builtin_amdgcn_mfma_f32_16x16x32_f16(qh1, sh1, a, 0, 0, 0);
        a = __builtin_amdgcn_mfma_f32_16x16x32_f16(af0, vf0, a, 0, 0, 0);
        a = __builtin_amdgcn_mfma_f32_16x16x32_f16(af1, vf1, a, 0, 0, 0);
        nacc[et] = a;
    }
    // ---- out = num/den, head-LN, bf16 store ----
#pragma unroll
    for (int r = 0; r < 4; r++) {
        int i = w * 16 + q * 4 + r;
        float inv = 1.0f / (den1[i] + den2[i] + 1e-6f);
        float o[4];
        float s = 0.f, s2 = 0.f;
#pragma unroll
        for (int et = 0; et < 4; et++) {
            float v = nacc[et][r] * inv;
            o[et] = v;
            s += v;
            s2 += v * v;
        }
        s  += __shfl_xor(s, 1);  s  += __shfl_xor(s, 2);
        s  += __shfl_xor(s, 4);  s  += __shfl_xor(s, 8);
        s2 += __shfl_xor(s2, 1); s2 += __shfl_xor(s2, 2);
        s2 += __shfl_xor(s2, 4); s2 += __shfl_xor(s2, 8);
        float mu = s * (1.0f / DH);
        float var = s2 * (1.0f / DH) - mu * mu;
        float rstd = rsqrtf(var + 1e-5f);
        size_t gb = (rowbase + i) * DD + h * DH;
#pragma unroll
        for (int et = 0; et < 4; et++) {
            int e = et * 16 + l16;
            attn_bf[gb + e] = f2bf((o[et] - mu) * rstd * mgs[e] + mbs[e]);
        }
    }
}

// ---------------------------------------------------------------------------
extern "C" void kernel_launch(void* const* d_in, const int* in_sizes, int n_in,
                              void* d_out, int out_size, void* d_ws, size_t ws_size,
                              hipStream_t stream) {
    const float* x    = (const float*)d_in[0];
    const float* Wqkv = (const float*)d_in[1];
    const float* bqkv = (const float*)d_in[2];
    const float* Wb1  = (const float*)d_in[3];
    const float* Wb2  = (const float*)d_in[4];
    const float* temperature = (const float*)d_in[5];
    const float* Wproj = (const float*)d_in[6];
    const float* bproj = (const float*)d_in[7];
    const float* ln_g = (const float*)d_in[8];
    const float* ln_b = (const float*)d_in[9];
    const float* mn_g = (const float*)d_in[10];
    const float* mn_b = (const float*)d_in[11];

    float* out0     = (float*)d_out;                    // (B,L,D)
    float* gate_out = out0 + (size_t)BL * DD;           // (B,L,H)

    float* ws = (float*)d_ws;
    float* qkv    = ws;                                   // 4,718,592 f32
    float* h1     = qkv + (size_t)BL * D3;                //   262,144
    float* states = h1 + (size_t)BL * RR;                 // 1,597,440
    unsigned short* xnbf  = (unsigned short*)(states + (size_t)BB * HH * NC * 4160);
    unsigned short* xbf    = xnbf + (size_t)BL * DD;
    unsigned short* attnbf = xbf + (size_t)BL * DD;
    unsigned short* wqkvt  = attnbf + (size_t)BL * DD;
    unsigned short* wb1t   = wqkvt + (size_t)D3 * DD;
    unsigned short* wprojt = wb1t + (size_t)DD * RR;

    // 1. LN + x->bf16 + all weight transposes
    prep_kernel<<<4448, 256, 0, stream>>>(x, ln_g, ln_b, xnbf, xbf,
                                          Wqkv, Wb1, Wproj, wqkvt, wb1t, wprojt);
    // 2. qkv GEMM + Wb1 GEMM fused
    gemm_big_kernel<<<304, 256, 0, stream>>>(xnbf, wqkvt, bqkv, qkv, xbf, wb1t, h1);
    // 3. chunk-local states (split-fp16 MFMA + in-block gate, 384 blocks)
    passA_kernel<<<BB * HH * NC, 256, 0, stream>>>(qkv, h1, Wb2, temperature, gate_out, states);
    // 4. replay (split-fp16 MFMA + in-block gate) + inline prefix + head-LN -> bf16
    passC_kernel<<<BB * HH * NC, 256, 0, stream>>>(qkv, h1, Wb2, temperature, states, mn_g, mn_b, attnbf);
    // 5. out = attn @ Wproj + bproj
    gemm64_kernel<<<dim3(DD / 64, BL / 64), 256, 0, stream>>>(attnbf, wprojt, bproj, out0, BL, DD, DD);
}

// Round 10
// 147.017 us; speedup vs baseline: 1.5948x; 1.0381x over previous
//
#include <hip/hip_runtime.h>
#include <hip/hip_bf16.h>
#include <math.h>

// Problem constants
#define BB 4
#define LL 512
#define DD 768
#define HH 12
#define DH 64
#define RR 128
#define BL (BB*LL)      // 2048
#define D3 (3*DD)       // 2304
#define NC 8            // chunks over L
#define CT 64           // chunk length
#define SP 72           // LDS row stride (elems), 144 B, 16B-aligned rows
#define PI_F 3.14159265358979323846f

typedef short bf16x8 __attribute__((ext_vector_type(8)));
typedef _Float16 f16x8 __attribute__((ext_vector_type(8)));
typedef float f32x4 __attribute__((ext_vector_type(4)));

__device__ __forceinline__ float sigmoidf_(float x) { return 1.0f / (1.0f + expf(-x)); }
__device__ __forceinline__ float elu1f_(float x)    { return x > 0.0f ? x + 1.0f : expf(x); }
__device__ __forceinline__ unsigned short f2bf(float f) {
    unsigned u = __float_as_uint(f);
    unsigned r = u + 0x7FFF + ((u >> 16) & 1);
    return (unsigned short)(r >> 16);
}
// fp16 convert (RNE) + helpers
__device__ __forceinline__ unsigned short f2h(float f) {
    _Float16 h = (_Float16)f;
    return *(unsigned short*)&h;
}
__device__ __forceinline__ float h2f(unsigned short u) {
    _Float16 h = *(_Float16*)&u;
    return (float)h;
}
__device__ __forceinline__ int packh2(float lo, float hi) {
    return (int)f2h(lo) | ((int)f2h(hi) << 16);
}
// split fp32 -> fp16 hi + fp16 lo residual
__device__ __forceinline__ void splith(float v, unsigned short& h, unsigned short& l) {
    h = f2h(v);
    l = f2h(v - h2f(h));
}
// async global->LDS DMA, 16 B per lane
__device__ __forceinline__ void gll16(const void* g, void* l) {
    __builtin_amdgcn_global_load_lds(
        (const __attribute__((address_space(1))) void*)g,
        (__attribute__((address_space(3))) void*)l, 16, 0, 0);
}

// In-block gate computation for 64 rows of head h.
template <bool WRITE_GATE>
__device__ __forceinline__ void compute_gate_block(int t, int h, size_t rowbase,
                                                   const float* __restrict__ h1,
                                                   const float* __restrict__ Wb2,
                                                   const float* __restrict__ temperature,
                                                   float* __restrict__ w2h,
                                                   float* __restrict__ wsm,
                                                   float* __restrict__ gate_out) {
    for (int i = t; i < 512; i += 256)
        w2h[i] = Wb2[(i >> 2) * 60 + h * 5 + (i & 3)];
    __syncthreads();
    int row = t >> 2, part = t & 3;
    const float* h1r = &h1[(rowbase + row) * RR + part * 32];
    float p0 = 0.f, p1 = 0.f, p2 = 0.f, p3 = 0.f;
#pragma unroll 8
    for (int kk = 0; kk < 32; kk++) {
        float hv = h1r[kk];
        const float* wp = &w2h[(part * 32 + kk) * 4];
        p0 += hv * wp[0];
        p1 += hv * wp[1];
        p2 += hv * wp[2];
        p3 += hv * wp[3];
    }
    p0 += __shfl_xor(p0, 1); p0 += __shfl_xor(p0, 2);
    p1 += __shfl_xor(p1, 1); p1 += __shfl_xor(p1, 2);
    p2 += __shfl_xor(p2, 1); p2 += __shfl_xor(p2, 2);
    p3 += __shfl_xor(p3, 1); p3 += __shfl_xor(p3, 2);
    if (part == 0) {
        float temp = fminf(fmaxf(temperature[0], 0.1f), 2.0f);
        float sa = sigmoidf_(p0);
        float sp = tanhf(p1) * PI_F;
        float ca = sigmoidf_(p2);
        float cp = tanhf(p3) * PI_F;
        float itf = tanhf(sa * ca * cosf(sp - cp)) * temp;
        float gt = sigmoidf_(itf);
        wsm[row] = 1.0f + gt;
        if (WRITE_GATE) gate_out[(rowbase + row) * HH + h] = gt;
    }
    __syncthreads();
}

// ---------------------------------------------------------------------------
// Kernel 1 (prep, fused): bid<2048 -> row-LN of x (bf16) + raw x (bf16);
// bid>=2048 -> weight transposes f32 [K][N] -> bf16 [N][K].
// ---------------------------------------------------------------------------
__global__ __launch_bounds__(256) void prep_kernel(const float* __restrict__ x,
                                                   const float* __restrict__ g,
                                                   const float* __restrict__ b,
                                                   unsigned short* __restrict__ xn,
                                                   unsigned short* __restrict__ xb,
                                                   const float* __restrict__ Wqkv,
                                                   const float* __restrict__ Wb1,
                                                   const float* __restrict__ Wproj,
                                                   unsigned short* __restrict__ wqkvt,
                                                   unsigned short* __restrict__ wb1t,
                                                   unsigned short* __restrict__ wprojt) {
    __shared__ float smem[32 * 33];
    int bid = blockIdx.x;
    int t = threadIdx.x;
    if (bid < 2048) {
        int row = bid;
        int w = t >> 6, lane = t & 63;
        float v[3];
        float s = 0.f, s2 = 0.f;
#pragma unroll
        for (int i = 0; i < 3; i++) {
            v[i] = x[(size_t)row * DD + t + i * 256];
            s += v[i];
            s2 += v[i] * v[i];
        }
#pragma unroll
        for (int off = 1; off < 64; off <<= 1) {
            s  += __shfl_xor(s, off);
            s2 += __shfl_xor(s2, off);
        }
        if (lane == 0) { smem[w] = s; smem[4 + w] = s2; }
        __syncthreads();
        s  = smem[0] + smem[1] + smem[2] + smem[3];
        s2 = smem[4] + smem[5] + smem[6] + smem[7];
        float mu = s * (1.0f / DD);
        float var = s2 * (1.0f / DD) - mu * mu;
        float rstd = rsqrtf(var + 1e-5f);
#pragma unroll
        for (int i = 0; i < 3; i++) {
            int col = t + i * 256;
            xn[(size_t)row * DD + col] = f2bf((v[i] - mu) * rstd * g[col] + b[col]);
            xb[(size_t)row * DD + col] = f2bf(v[i]);
        }
    } else {
        bid -= 2048;
        const float* in; unsigned short* out; int K, N, bx, by;
        if (bid < 1728)      { in = Wqkv;  out = wqkvt;  K = DD; N = D3; bx = bid % 72; by = bid / 72; }
        else if (bid < 1824) { bid -= 1728; in = Wb1;  out = wb1t;  K = DD; N = RR; bx = bid % 4;  by = bid / 4; }
        else                 { bid -= 1824; in = Wproj; out = wprojt; K = DD; N = DD; bx = bid % 24; by = bid / 24; }
        int n0 = bx * 32, k0 = by * 32;
        int tx = t & 31, ty = t >> 5;
        float (*tile)[33] = (float(*)[33])smem;
#pragma unroll
        for (int i = 0; i < 4; i++)
            tile[ty + i * 8][tx] = in[(size_t)(k0 + ty + i * 8) * N + n0 + tx];
        __syncthreads();
#pragma unroll
        for (int i = 0; i < 4; i++)
            out[(size_t)(n0 + ty + i * 8) * K + k0 + tx] = f2bf(tile[tx][ty + i * 8]);
    }
}

// ---------------------------------------------------------------------------
// Kernel 2 (fused QKV + Wb1 GEMM): 64x128 tile (finer for tail balance),
// gll16 staging, XOR-swizzled unpadded LDS.
// Blocks 0..575: qkv (M 2048/64 x N 2304/128).  Blocks 576..607: h1 (N=128).
// ---------------------------------------------------------------------------
__global__ __launch_bounds__(256) void gemm_big_kernel(const unsigned short* __restrict__ xn,
                                                       const unsigned short* __restrict__ wqkvt,
                                                       const float* __restrict__ bqkv,
                                                       float* __restrict__ qkv,
                                                       const unsigned short* __restrict__ xb,
                                                       const unsigned short* __restrict__ wb1t,
                                                       float* __restrict__ h1) {
    __shared__ __align__(16) unsigned short As[64 * 32];
    __shared__ __align__(16) unsigned short Bs[128 * 32];
    int bid = blockIdx.x;
    const unsigned short *A, *Bt;
    const float* bias;
    float* C;
    int N, act, bm, bn;
    if (bid < 576) { A = xn; Bt = wqkvt; bias = bqkv; C = qkv; N = D3; act = 0;
                     bn = (bid % 18) * 128; bm = (bid / 18) * 64; }
    else           { int b2 = bid - 576; A = xb; Bt = wb1t; bias = nullptr; C = h1; N = RR; act = 1;
                     bm = b2 * 64; bn = 0; }
    const int K = DD;

    int t = threadIdx.x;
    int lane = t & 63, w = t >> 6;
    int wrow = w >> 1, wcol = w & 1;         // 2x2 wave grid over 64x128
    int quad = lane >> 4, l16 = lane & 15;

    f32x4 acc[2][4];
#pragma unroll
    for (int i = 0; i < 2; i++)
#pragma unroll
        for (int j = 0; j < 4; j++)
            acc[i][j] = (f32x4){0.f, 0.f, 0.f, 0.f};

    int swz_s = ((lane >> 2) & 3) ^ ((lane >> 4) & 3);
    int gsel = ((lane & 3) ^ swz_s) * 8;
    const unsigned short* a0 = A  + (size_t)(bm + w * 16 + (lane >> 2)) * K + gsel;
    const unsigned short* b0 = Bt + (size_t)(bn + w * 16 + (lane >> 2)) * K + gsel;
    const unsigned short* b1 = b0 + (size_t)64 * K;
    unsigned short* lA0 = &As[(w * 16) * 32];
    unsigned short* lB0 = &Bs[(w * 16) * 32];
    unsigned short* lB1 = &Bs[(64 + w * 16) * 32];

    int swz_f = (l16 & 3) ^ ((l16 >> 2) & 3);
    int foff = (quad ^ swz_f) * 8;

    for (int k0 = 0; k0 < K; k0 += 32) {
        __syncthreads();
        gll16(a0 + k0, lA0);
        gll16(b0 + k0, lB0);
        gll16(b1 + k0, lB1);
        __syncthreads();
        bf16x8 af[2], bfr[4];
#pragma unroll
        for (int mi = 0; mi < 2; mi++)
            af[mi] = *(const bf16x8*)&As[(wrow * 32 + mi * 16 + l16) * 32 + foff];
#pragma unroll
        for (int ni = 0; ni < 4; ni++)
            bfr[ni] = *(const bf16x8*)&Bs[(wcol * 64 + ni * 16 + l16) * 32 + foff];
#pragma unroll
        for (int mi = 0; mi < 2; mi++)
#pragma unroll
            for (int ni = 0; ni < 4; ni++)
                acc[mi][ni] = __builtin_amdgcn_mfma_f32_16x16x32_bf16(af[mi], bfr[ni], acc[mi][ni], 0, 0, 0);
    }

#pragma unroll
    for (int mi = 0; mi < 2; mi++) {
#pragma unroll
        for (int r = 0; r < 4; r++) {
            int row = bm + wrow * 32 + mi * 16 + quad * 4 + r;
#pragma unroll
            for (int ni = 0; ni < 4; ni++) {
                int col = bn + wcol * 64 + ni * 16 + l16;
                float v = acc[mi][ni][r];
                if (act == 0) v += bias[col];
                else          v = v * sigmoidf_(v);
                C[(size_t)row * N + col] = v;
            }
        }
    }
}

// ---------------------------------------------------------------------------
// Kernel 2b: 64x64-tile GEMM for proj (N=768 -> 384 blocks).
// ---------------------------------------------------------------------------
__global__ __launch_bounds__(256) void gemm64_kernel(const unsigned short* __restrict__ A,
                                                     const unsigned short* __restrict__ Bt,
                                                     const float* __restrict__ bias,
                                                     float* __restrict__ C,
                                                     int M, int N, int K) {
    __shared__ __align__(16) unsigned short As[64 * 32];
    __shared__ __align__(16) unsigned short Bs[64 * 32];
    int t = threadIdx.x;
    int lane = t & 63, w = t >> 6;
    int wrow = w >> 1, wcol = w & 1;
    int quad = lane >> 4, l16 = lane & 15;
    int bm = blockIdx.y * 64, bn = blockIdx.x * 64;

    f32x4 acc[2][2];
#pragma unroll
    for (int i = 0; i < 2; i++)
#pragma unroll
        for (int j = 0; j < 2; j++)
            acc[i][j] = (f32x4){0.f, 0.f, 0.f, 0.f};

    int swz_s = ((lane >> 2) & 3) ^ ((lane >> 4) & 3);
    int gsel = ((lane & 3) ^ swz_s) * 8;
    const unsigned short* a0 = A  + (size_t)(bm + w * 16 + (lane >> 2)) * K + gsel;
    const unsigned short* b0 = Bt + (size_t)(bn + w * 16 + (lane >> 2)) * K + gsel;
    unsigned short* lA0 = &As[(w * 16) * 32];
    unsigned short* lB0 = &Bs[(w * 16) * 32];

    int swz_f = (l16 & 3) ^ ((l16 >> 2) & 3);
    int foff = (quad ^ swz_f) * 8;

    for (int k0 = 0; k0 < K; k0 += 32) {
        __syncthreads();
        gll16(a0 + k0, lA0);
        gll16(b0 + k0, lB0);
        __syncthreads();
        bf16x8 af[2], bfr[2];
#pragma unroll
        for (int mi = 0; mi < 2; mi++)
            af[mi] = *(const bf16x8*)&As[(wrow * 32 + mi * 16 + l16) * 32 + foff];
#pragma unroll
        for (int ni = 0; ni < 2; ni++)
            bfr[ni] = *(const bf16x8*)&Bs[(wcol * 32 + ni * 16 + l16) * 32 + foff];
#pragma unroll
        for (int mi = 0; mi < 2; mi++)
#pragma unroll
            for (int ni = 0; ni < 2; ni++)
                acc[mi][ni] = __builtin_amdgcn_mfma_f32_16x16x32_bf16(af[mi], bfr[ni], acc[mi][ni], 0, 0, 0);
    }

#pragma unroll
    for (int mi = 0; mi < 2; mi++) {
#pragma unroll
        for (int r = 0; r < 4; r++) {
            int row = bm + wrow * 32 + mi * 16 + quad * 4 + r;
#pragma unroll
            for (int ni = 0; ni < 2; ni++) {
                int col = bn + wcol * 32 + ni * 16 + l16;
                C[(size_t)row * N + col] = acc[mi][ni][r] + bias[col];
            }
        }
    }
}

// ---------------------------------------------------------------------------
// Kernel 4 (pass A, split-fp16 MFMA + in-block gate)
// ---------------------------------------------------------------------------
__global__ __launch_bounds__(256) void passA_kernel(const float* __restrict__ qkv,
                                                    const float* __restrict__ h1,
                                                    const float* __restrict__ Wb2,
                                                    const float* __restrict__ temperature,
                                                    float* __restrict__ gate_out,
                                                    float* __restrict__ states) {
    int blk = blockIdx.x;
    int c = blk % NC, bh = blk / NC;
    int b = bh / HH, h = bh % HH;
    __shared__ __align__(16) unsigned short KTh[64 * SP], KTl[64 * SP];   // K^T[d][j]
    __shared__ __align__(16) unsigned short VTh[64 * SP], VTl[64 * SP];   // (V*w)^T[e][j]
    __shared__ float wsm[64];
    __shared__ float zpart[4][64];
    __shared__ float w2h[512];
    int t = threadIdx.x;
    size_t rowbase = (size_t)b * LL + c * CT;

    compute_gate_block<true>(t, h, rowbase, h1, Wb2, temperature, w2h, wsm, gate_out);

    {
        int d = t & 63, jg = t >> 6;
        const float* kbase = &qkv[(rowbase + jg * 16) * D3 + DD + h * DH + d];
        const float* vbase = kbase + DD;
        float zl = 0.f;
#pragma unroll
        for (int s = 0; s < 8; s++) {
            int j = jg * 16 + 2 * s;
            float k0 = elu1f_(kbase[(2 * s) * D3]);
            float k1 = elu1f_(kbase[(2 * s + 1) * D3]);
            zl += k0 + k1;
            unsigned short h0, l0, h1v, l1;
            splith(k0, h0, l0); splith(k1, h1v, l1);
            *(int*)&KTh[d * SP + j] = (int)h0 | ((int)h1v << 16);
            *(int*)&KTl[d * SP + j] = (int)l0 | ((int)l1 << 16);
            float v0 = vbase[(2 * s) * D3] * wsm[j];
            float v1 = vbase[(2 * s + 1) * D3] * wsm[j + 1];
            splith(v0, h0, l0); splith(v1, h1v, l1);
            *(int*)&VTh[d * SP + j] = (int)h0 | ((int)h1v << 16);
            *(int*)&VTl[d * SP + j] = (int)l0 | ((int)l1 << 16);
        }
        zpart[jg][d] = zl;
    }
    __syncthreads();
    int lane = t & 63, w = t >> 6;
    int q = lane >> 4, l16 = lane & 15;
    float* st = states + (size_t)(bh * NC + c) * 4160;
    int vrow = (w * 16 + l16) * SP;
    const f16x8 vh0 = *(const f16x8*)&VTh[vrow + q * 8];
    const f16x8 vh1 = *(const f16x8*)&VTh[vrow + 32 + q * 8];
    const f16x8 vl0 = *(const f16x8*)&VTl[vrow + q * 8];
    const f16x8 vl1 = *(const f16x8*)&VTl[vrow + 32 + q * 8];
#pragma unroll
    for (int dt = 0; dt < 4; dt++) {
        int krow = (dt * 16 + l16) * SP;
        const f16x8 kh0 = *(const f16x8*)&KTh[krow + q * 8];
        const f16x8 kh1 = *(const f16x8*)&KTh[krow + 32 + q * 8];
        const f16x8 kl0 = *(const f16x8*)&KTl[krow + q * 8];
        const f16x8 kl1 = *(const f16x8*)&KTl[krow + 32 + q * 8];
        f32x4 a = (f32x4){0.f, 0.f, 0.f, 0.f};
        a = __builtin_amdgcn_mfma_f32_16x16x32_f16(vh0, kl0, a, 0, 0, 0);
        a = __builtin_amdgcn_mfma_f32_16x16x32_f16(vh1, kl1, a, 0, 0, 0);
        a = __builtin_amdgcn_mfma_f32_16x16x32_f16(vl0, kh0, a, 0, 0, 0);
        a = __builtin_amdgcn_mfma_f32_16x16x32_f16(vl1, kh1, a, 0, 0, 0);
        a = __builtin_amdgcn_mfma_f32_16x16x32_f16(vh0, kh0, a, 0, 0, 0);
        a = __builtin_amdgcn_mfma_f32_16x16x32_f16(vh1, kh1, a, 0, 0, 0);
#pragma unroll
        for (int r = 0; r < 4; r++)
            st[(w * 16 + q * 4 + r) * 64 + dt * 16 + l16] = a[r];
    }
    if (t < 64) st[4096 + t] = zpart[0][t] + zpart[1][t] + zpart[2][t] + zpart[3][t];
}

// ---------------------------------------------------------------------------
// Kernel 5 (pass C, split-fp16 MFMA + in-block gate + head-LN fused)
// den2 computed from Q fragment registers (no LDS re-read).
// ---------------------------------------------------------------------------
__global__ __launch_bounds__(256) void passC_kernel(const float* __restrict__ qkv,
                                                    const float* __restrict__ h1,
                                                    const float* __restrict__ Wb2,
                                                    const float* __restrict__ temperature,
                                                    const float* __restrict__ states,
                                                    const float* __restrict__ mg,
                                                    const float* __restrict__ mb,
                                                    unsigned short* __restrict__ attn_bf) {
    int blk = blockIdx.x;
    int c = blk % NC, bh = blk / NC;
    int b = bh / HH, h = bh % HH;
    __shared__ __align__(16) unsigned short Qh[64 * SP], Ql[64 * SP];  // Q[i][d]
    __shared__ __align__(16) unsigned short Kh[64 * SP], Kl[64 * SP];  // K[j][d]
    __shared__ __align__(16) unsigned short VT[64 * SP];               // V^T[e][j]
    __shared__ __align__(16) unsigned short Sh[64 * SP], Sl[64 * SP];  // S_prev^T[e][d]
    __shared__ __align__(16) unsigned short At[64 * SP];               // Atilde[i][j]
    __shared__ float wsm[64], zb[64], den1[64], den2[64], mgs[64], mbs[64];
    __shared__ float w2h[512];
    int t = threadIdx.x;
    size_t rowbase = (size_t)b * LL + c * CT;

    compute_gate_block<false>(t, h, rowbase, h1, Wb2, temperature, w2h, wsm, nullptr);

    // ---- stage Q, K rows (elu, split fp16) ----
    {
        int j = t >> 2, f = t & 3;
        const float* qr = &qkv[(rowbase + j) * D3 + h * DH];
#pragma unroll
        for (int i2 = 0; i2 < 4; i2++) {
            int off = f * 16 + i2 * 4;
            float4 q4 = *(const float4*)&qr[off];
            ushort4 h4, l4;
            splith(elu1f_(q4.x), h4.x, l4.x); splith(elu1f_(q4.y), h4.y, l4.y);
            splith(elu1f_(q4.z), h4.z, l4.z); splith(elu1f_(q4.w), h4.w, l4.w);
            *(ushort4*)&Qh[j * SP + off] = h4;
            *(ushort4*)&Ql[j * SP + off] = l4;
            float4 k4 = *(const float4*)&qr[DD + off];
            splith(elu1f_(k4.x), h4.x, l4.x); splith(elu1f_(k4.y), h4.y, l4.y);
            splith(elu1f_(k4.z), h4.z, l4.z); splith(elu1f_(k4.w), h4.w, l4.w);
            *(ushort4*)&Kh[j * SP + off] = h4;
            *(ushort4*)&Kl[j * SP + off] = l4;
        }
    }
    // ---- stage V^T (fp16 hi only) ----
    {
        int e = t & 63, jg = t >> 6;
        const float* vbase = &qkv[(rowbase + jg * 16) * D3 + 2 * DD + h * DH + e];
#pragma unroll
        for (int s = 0; s < 8; s++) {
            int j = jg * 16 + 2 * s;
            float v0 = vbase[(2 * s) * D3];
            float v1 = vbase[(2 * s + 1) * D3];
            *(int*)&VT[e * SP + j] = packh2(v0, v1);
        }
    }
    // ---- stage S_prev^T = fp32 sum of chunk-local states -> split fp16 ----
    {
        int e = t >> 2, dbase = (t & 3) * 16;
        float acc[16];
#pragma unroll
        for (int i = 0; i < 16; i++) acc[i] = 0.f;
        for (int cp = 0; cp < c; cp++) {
            const float* st = states + (size_t)(bh * NC + cp) * 4160 + t * 16;
#pragma unroll
            for (int g2 = 0; g2 < 4; g2++) {
                float4 v4 = *(const float4*)&st[g2 * 4];
                acc[g2 * 4 + 0] += v4.x; acc[g2 * 4 + 1] += v4.y;
                acc[g2 * 4 + 2] += v4.z; acc[g2 * 4 + 3] += v4.w;
            }
        }
#pragma unroll
        for (int g2 = 0; g2 < 4; g2++) {
            ushort4 h4, l4;
            splith(acc[g2 * 4 + 0], h4.x, l4.x); splith(acc[g2 * 4 + 1], h4.y, l4.y);
            splith(acc[g2 * 4 + 2], h4.z, l4.z); splith(acc[g2 * 4 + 3], h4.w, l4.w);
            *(ushort4*)&Sh[e * SP + dbase + g2 * 4] = h4;
            *(ushort4*)&Sl[e * SP + dbase + g2 * 4] = l4;
        }
    }
    if (t < 64) {
        float z = 0.f;
        for (int cp = 0; cp < c; cp++)
            z += states[(size_t)(bh * NC + cp) * 4160 + 4096 + t];
        zb[t] = z;
        mgs[t] = mg[t];
        mbs[t] = mb[t];
    }
    __syncthreads();

    int lane = t & 63, w = t >> 6;
    int q = lane >> 4, l16 = lane & 15;
    int qrow = (w * 16 + l16) * SP;
    const f16x8 qh0 = *(const f16x8*)&Qh[qrow + q * 8];
    const f16x8 qh1 = *(const f16x8*)&Qh[qrow + 32 + q * 8];
    const f16x8 ql0 = *(const f16x8*)&Ql[qrow + q * 8];
    const f16x8 ql1 = *(const f16x8*)&Ql[qrow + 32 + q * 8];

    // ---- scores = Q K^T (3-term split) ----
    f32x4 sa[4];
#pragma unroll
    for (int jt = 0; jt < 4; jt++) {
        int krow = (jt * 16 + l16) * SP;
        const f16x8 kh0 = *(const f16x8*)&Kh[krow + q * 8];
        const f16x8 kh1 = *(const f16x8*)&Kh[krow + 32 + q * 8];
        const f16x8 kl0 = *(const f16x8*)&Kl[krow + q * 8];
        const f16x8 kl1 = *(const f16x8*)&Kl[krow + 32 + q * 8];
        f32x4 a = (f32x4){0.f, 0.f, 0.f, 0.f};
        a = __builtin_amdgcn_mfma_f32_16x16x32_f16(qh0, kl0, a, 0, 0, 0);
        a = __builtin_amdgcn_mfma_f32_16x16x32_f16(qh1, kl1, a, 0, 0, 0);
        a = __builtin_amdgcn_mfma_f32_16x16x32_f16(ql0, kh0, a, 0, 0, 0);
        a = __builtin_amdgcn_mfma_f32_16x16x32_f16(ql1, kh1, a, 0, 0, 0);
        a = __builtin_amdgcn_mfma_f32_16x16x32_f16(qh0, kh0, a, 0, 0, 0);
        a = __builtin_amdgcn_mfma_f32_16x16x32_f16(qh1, kh1, a, 0, 0, 0);
        sa[jt] = a;
    }
    // ---- causal mask, w-scale, At (fp16), fp32 den_intra ----
    float den_p[4] = {0.f, 0.f, 0.f, 0.f};
#pragma unroll
    for (int jt = 0; jt < 4; jt++) {
        int j = jt * 16 + l16;
        float wj = wsm[j];
#pragma unroll
        for (int r = 0; r < 4; r++) {
            int i = w * 16 + q * 4 + r;
            float a = (j <= i) ? sa[jt][r] : 0.f;
            den_p[r] += a;
            At[i * SP + j] = f2h(a * wj);
        }
    }
#pragma unroll
    for (int r = 0; r < 4; r++) {
        den_p[r] += __shfl_xor(den_p[r], 1);
        den_p[r] += __shfl_xor(den_p[r], 2);
        den_p[r] += __shfl_xor(den_p[r], 4);
        den_p[r] += __shfl_xor(den_p[r], 8);
    }
    if (l16 == 0) {
#pragma unroll
        for (int r = 0; r < 4; r++) den1[w * 16 + q * 4 + r] = den_p[r];
    }
    // ---- den_inter = Q . z_prev, from Q fragment registers (fp32) ----
    {
        float dp = 0.f;
#pragma unroll
        for (int s = 0; s < 8; s++) {
            dp += ((float)qh0[s] + (float)ql0[s]) * zb[q * 8 + s];
            dp += ((float)qh1[s] + (float)ql1[s]) * zb[32 + q * 8 + s];
        }
        dp += __shfl_xor(dp, 16);
        dp += __shfl_xor(dp, 32);
        if (q == 0) den2[w * 16 + l16] = dp;
    }
    __syncthreads();   // At / den1 / den2 visible

    // ---- num = Q S_prev^T (3-term) + At V^T ----
    const f16x8 af0 = *(const f16x8*)&At[qrow + q * 8];
    const f16x8 af1 = *(const f16x8*)&At[qrow + 32 + q * 8];
    f32x4 nacc[4];
#pragma unroll
    for (int et = 0; et < 4; et++) {
        int erow = (et * 16 + l16) * SP;
        const f16x8 sh0 = *(const f16x8*)&Sh[erow + q * 8];
        const f16x8 sh1 = *(const f16x8*)&Sh[erow + 32 + q * 8];
        const f16x8 sl0 = *(const f16x8*)&Sl[erow + q * 8];
        const f16x8 sl1 = *(const f16x8*)&Sl[erow + 32 + q * 8];
        const f16x8 vf0 = *(const f16x8*)&VT[erow + q * 8];
        const f16x8 vf1 = *(const f16x8*)&VT[erow + 32 + q * 8];
        f32x4 a = (f32x4){0.f, 0.f, 0.f, 0.f};
        a = __builtin_amdgcn_mfma_f32_16x16x32_f16(qh0, sl0, a, 0, 0, 0);
        a = __builtin_amdgcn_mfma_f32_16x16x32_f16(qh1, sl1, a, 0, 0, 0);
        a = __builtin_amdgcn_mfma_f32_16x16x32_f16(ql0, sh0, a, 0, 0, 0);
        a = __builtin_amdgcn_mfma_f32_16x16x32_f16(ql1, sh1, a, 0, 0, 0);
        a = __builtin_amdgcn_mfma_f32_16x16x32_f16(qh0, sh0, a, 0, 0, 0);
        a = __builtin_amdgcn_mfma_f32_16x16x32_f16(qh1, sh1, a, 0, 0, 0);
        a = __builtin_amdgcn_mfma_f32_16x16x32_f16(af0, vf0, a, 0, 0, 0);
        a = __builtin_amdgcn_mfma_f32_16x16x32_f16(af1, vf1, a, 0, 0, 0);
        nacc[et] = a;
    }
    // ---- out = num/den, head-LN, bf16 store ----
#pragma unroll
    for (int r = 0; r < 4; r++) {
        int i = w * 16 + q * 4 + r;
        float inv = 1.0f / (den1[i] + den2[i] + 1e-6f);
        float o[4];
        float s = 0.f, s2 = 0.f;
#pragma unroll
        for (int et = 0; et < 4; et++) {
            float v = nacc[et][r] * inv;
            o[et] = v;
            s += v;
            s2 += v * v;
        }
        s  += __shfl_xor(s, 1);  s  += __shfl_xor(s, 2);
        s  += __shfl_xor(s, 4);  s  += __shfl_xor(s, 8);
        s2 += __shfl_xor(s2, 1); s2 += __shfl_xor(s2, 2);
        s2 += __shfl_xor(s2, 4); s2 += __shfl_xor(s2, 8);
        float mu = s * (1.0f / DH);
        float var = s2 * (1.0f / DH) - mu * mu;
        float rstd = rsqrtf(var + 1e-5f);
        size_t gb = (rowbase + i) * DD + h * DH;
#pragma unroll
        for (int et = 0; et < 4; et++) {
            int e = et * 16 + l16;
            attn_bf[gb + e] = f2bf((o[et] - mu) * rstd * mgs[e] + mbs[e]);
        }
    }
}

// ---------------------------------------------------------------------------
extern "C" void kernel_launch(void* const* d_in, const int* in_sizes, int n_in,
                              void* d_out, int out_size, void* d_ws, size_t ws_size,
                              hipStream_t stream) {
    const float* x    = (const float*)d_in[0];
    const float* Wqkv = (const float*)d_in[1];
    const float* bqkv = (const float*)d_in[2];
    const float* Wb1  = (const float*)d_in[3];
    const float* Wb2  = (const float*)d_in[4];
    const float* temperature = (const float*)d_in[5];
    const float* Wproj = (const float*)d_in[6];
    const float* bproj = (const float*)d_in[7];
    const float* ln_g = (const float*)d_in[8];
    const float* ln_b = (const float*)d_in[9];
    const float* mn_g = (const float*)d_in[10];
    const float* mn_b = (const float*)d_in[11];

    float* out0     = (float*)d_out;                    // (B,L,D)
    float* gate_out = out0 + (size_t)BL * DD;           // (B,L,H)

    float* ws = (float*)d_ws;
    float* qkv    = ws;                                   // 4,718,592 f32
    float* h1     = qkv + (size_t)BL * D3;                //   262,144
    float* states = h1 + (size_t)BL * RR;                 // 1,597,440
    unsigned short* xnbf  = (unsigned short*)(states + (size_t)BB * HH * NC * 4160);
    unsigned short* xbf    = xnbf + (size_t)BL * DD;
    unsigned short* attnbf = xbf + (size_t)BL * DD;
    unsigned short* wqkvt  = attnbf + (size_t)BL * DD;
    unsigned short* wb1t   = wqkvt + (size_t)D3 * DD;
    unsigned short* wprojt = wb1t + (size_t)DD * RR;

    // 1. LN + x->bf16 + all weight transposes
    prep_kernel<<<4448, 256, 0, stream>>>(x, ln_g, ln_b, xnbf, xbf,
                                          Wqkv, Wb1, Wproj, wqkvt, wb1t, wprojt);
    // 2. qkv GEMM + Wb1 GEMM fused (64x128 tiles, 608 blocks)
    gemm_big_kernel<<<608, 256, 0, stream>>>(xnbf, wqkvt, bqkv, qkv, xbf, wb1t, h1);
    // 3. chunk-local states (split-fp16 MFMA + in-block gate, 384 blocks)
    passA_kernel<<<BB * HH * NC, 256, 0, stream>>>(qkv, h1, Wb2, temperature, gate_out, states);
    // 4. replay (split-fp16 MFMA + in-block gate) + inline prefix + head-LN -> bf16
    passC_kernel<<<BB * HH * NC, 256, 0, stream>>>(qkv, h1, Wb2, temperature, states, mn_g, mn_b, attnbf);
    // 5. out = attn @ Wproj + bproj
    gemm64_kernel<<<dim3(DD / 64, BL / 64), 256, 0, stream>>>(attnbf, wprojt, bproj, out0, BL, DD, DD);
}

// Round 11
// 146.001 us; speedup vs baseline: 1.6059x; 1.0070x over previous
//
#include <hip/hip_runtime.h>
#include <hip/hip_bf16.h>
#include <math.h>

// Problem constants
#define BB 4
#define LL 512
#define DD 768
#define HH 12
#define DH 64
#define RR 128
#define BL (BB*LL)      // 2048
#define D3 (3*DD)       // 2304
#define NC 8            // chunks over L
#define CT 64           // chunk length
#define SP 72           // LDS row stride (elems), 144 B, 16B-aligned rows
#define PI_F 3.14159265358979323846f

typedef short bf16x8 __attribute__((ext_vector_type(8)));
typedef _Float16 f16x8 __attribute__((ext_vector_type(8)));
typedef float f32x4 __attribute__((ext_vector_type(4)));

__device__ __forceinline__ float sigmoidf_(float x) { return 1.0f / (1.0f + expf(-x)); }
__device__ __forceinline__ float elu1f_(float x)    { return x > 0.0f ? x + 1.0f : expf(x); }
__device__ __forceinline__ unsigned short f2bf(float f) {
    unsigned u = __float_as_uint(f);
    unsigned r = u + 0x7FFF + ((u >> 16) & 1);
    return (unsigned short)(r >> 16);
}
// fp16 convert (RNE) + helpers
__device__ __forceinline__ unsigned short f2h(float f) {
    _Float16 h = (_Float16)f;
    return *(unsigned short*)&h;
}
__device__ __forceinline__ float h2f(unsigned short u) {
    _Float16 h = *(_Float16*)&u;
    return (float)h;
}
__device__ __forceinline__ int packh2(float lo, float hi) {
    return (int)f2h(lo) | ((int)f2h(hi) << 16);
}
// split fp32 -> fp16 hi + fp16 lo residual
__device__ __forceinline__ void splith(float v, unsigned short& h, unsigned short& l) {
    h = f2h(v);
    l = f2h(v - h2f(h));
}
// async global->LDS DMA, 16 B per lane
__device__ __forceinline__ void gll16(const void* g, void* l) {
    __builtin_amdgcn_global_load_lds(
        (const __attribute__((address_space(1))) void*)g,
        (__attribute__((address_space(3))) void*)l, 16, 0, 0);
}

// In-block gate computation for 64 rows of head h.
template <bool WRITE_GATE>
__device__ __forceinline__ void compute_gate_block(int t, int h, size_t rowbase,
                                                   const float* __restrict__ h1,
                                                   const float* __restrict__ Wb2,
                                                   const float* __restrict__ temperature,
                                                   float* __restrict__ w2h,
                                                   float* __restrict__ wsm,
                                                   float* __restrict__ gate_out) {
    for (int i = t; i < 512; i += 256)
        w2h[i] = Wb2[(i >> 2) * 60 + h * 5 + (i & 3)];
    __syncthreads();
    int row = t >> 2, part = t & 3;
    const float* h1r = &h1[(rowbase + row) * RR + part * 32];
    float p0 = 0.f, p1 = 0.f, p2 = 0.f, p3 = 0.f;
#pragma unroll 8
    for (int kk = 0; kk < 32; kk++) {
        float hv = h1r[kk];
        const float* wp = &w2h[(part * 32 + kk) * 4];
        p0 += hv * wp[0];
        p1 += hv * wp[1];
        p2 += hv * wp[2];
        p3 += hv * wp[3];
    }
    p0 += __shfl_xor(p0, 1); p0 += __shfl_xor(p0, 2);
    p1 += __shfl_xor(p1, 1); p1 += __shfl_xor(p1, 2);
    p2 += __shfl_xor(p2, 1); p2 += __shfl_xor(p2, 2);
    p3 += __shfl_xor(p3, 1); p3 += __shfl_xor(p3, 2);
    if (part == 0) {
        float temp = fminf(fmaxf(temperature[0], 0.1f), 2.0f);
        float sa = sigmoidf_(p0);
        float sp = tanhf(p1) * PI_F;
        float ca = sigmoidf_(p2);
        float cp = tanhf(p3) * PI_F;
        float itf = tanhf(sa * ca * cosf(sp - cp)) * temp;
        float gt = sigmoidf_(itf);
        wsm[row] = 1.0f + gt;
        if (WRITE_GATE) gate_out[(rowbase + row) * HH + h] = gt;
    }
    __syncthreads();
}

// ---------------------------------------------------------------------------
// Kernel 1 (prep, fused): bid<2048 -> row-LN of x (bf16) + raw x (bf16);
// bid>=2048 -> weight transposes f32 [K][N] -> bf16 [N][K].
// ---------------------------------------------------------------------------
__global__ __launch_bounds__(256) void prep_kernel(const float* __restrict__ x,
                                                   const float* __restrict__ g,
                                                   const float* __restrict__ b,
                                                   unsigned short* __restrict__ xn,
                                                   unsigned short* __restrict__ xb,
                                                   const float* __restrict__ Wqkv,
                                                   const float* __restrict__ Wb1,
                                                   const float* __restrict__ Wproj,
                                                   unsigned short* __restrict__ wqkvt,
                                                   unsigned short* __restrict__ wb1t,
                                                   unsigned short* __restrict__ wprojt) {
    __shared__ float smem[32 * 33];
    int bid = blockIdx.x;
    int t = threadIdx.x;
    if (bid < 2048) {
        int row = bid;
        int w = t >> 6, lane = t & 63;
        float v[3];
        float s = 0.f, s2 = 0.f;
#pragma unroll
        for (int i = 0; i < 3; i++) {
            v[i] = x[(size_t)row * DD + t + i * 256];
            s += v[i];
            s2 += v[i] * v[i];
        }
#pragma unroll
        for (int off = 1; off < 64; off <<= 1) {
            s  += __shfl_xor(s, off);
            s2 += __shfl_xor(s2, off);
        }
        if (lane == 0) { smem[w] = s; smem[4 + w] = s2; }
        __syncthreads();
        s  = smem[0] + smem[1] + smem[2] + smem[3];
        s2 = smem[4] + smem[5] + smem[6] + smem[7];
        float mu = s * (1.0f / DD);
        float var = s2 * (1.0f / DD) - mu * mu;
        float rstd = rsqrtf(var + 1e-5f);
#pragma unroll
        for (int i = 0; i < 3; i++) {
            int col = t + i * 256;
            xn[(size_t)row * DD + col] = f2bf((v[i] - mu) * rstd * g[col] + b[col]);
            xb[(size_t)row * DD + col] = f2bf(v[i]);
        }
    } else {
        bid -= 2048;
        const float* in; unsigned short* out; int K, N, bx, by;
        if (bid < 1728)      { in = Wqkv;  out = wqkvt;  K = DD; N = D3; bx = bid % 72; by = bid / 72; }
        else if (bid < 1824) { bid -= 1728; in = Wb1;  out = wb1t;  K = DD; N = RR; bx = bid % 4;  by = bid / 4; }
        else                 { bid -= 1824; in = Wproj; out = wprojt; K = DD; N = DD; bx = bid % 24; by = bid / 24; }
        int n0 = bx * 32, k0 = by * 32;
        int tx = t & 31, ty = t >> 5;
        float (*tile)[33] = (float(*)[33])smem;
#pragma unroll
        for (int i = 0; i < 4; i++)
            tile[ty + i * 8][tx] = in[(size_t)(k0 + ty + i * 8) * N + n0 + tx];
        __syncthreads();
#pragma unroll
        for (int i = 0; i < 4; i++)
            out[(size_t)(n0 + ty + i * 8) * K + k0 + tx] = f2bf(tile[tx][ty + i * 8]);
    }
}

// ---------------------------------------------------------------------------
// Kernel 2 (fused QKV + Wb1 GEMM): 64x128 tile, gll16 staging, XOR-swizzled
// unpadded LDS. Blocks 0..575: qkv. Blocks 576..607: h1 = silu(xb @ Wb1).
// ---------------------------------------------------------------------------
__global__ __launch_bounds__(256) void gemm_big_kernel(const unsigned short* __restrict__ xn,
                                                       const unsigned short* __restrict__ wqkvt,
                                                       const float* __restrict__ bqkv,
                                                       float* __restrict__ qkv,
                                                       const unsigned short* __restrict__ xb,
                                                       const unsigned short* __restrict__ wb1t,
                                                       float* __restrict__ h1) {
    __shared__ __align__(16) unsigned short As[64 * 32];
    __shared__ __align__(16) unsigned short Bs[128 * 32];
    int bid = blockIdx.x;
    const unsigned short *A, *Bt;
    const float* bias;
    float* C;
    int N, act, bm, bn;
    if (bid < 576) { A = xn; Bt = wqkvt; bias = bqkv; C = qkv; N = D3; act = 0;
                     bn = (bid % 18) * 128; bm = (bid / 18) * 64; }
    else           { int b2 = bid - 576; A = xb; Bt = wb1t; bias = nullptr; C = h1; N = RR; act = 1;
                     bm = b2 * 64; bn = 0; }
    const int K = DD;

    int t = threadIdx.x;
    int lane = t & 63, w = t >> 6;
    int wrow = w >> 1, wcol = w & 1;         // 2x2 wave grid over 64x128
    int quad = lane >> 4, l16 = lane & 15;

    f32x4 acc[2][4];
#pragma unroll
    for (int i = 0; i < 2; i++)
#pragma unroll
        for (int j = 0; j < 4; j++)
            acc[i][j] = (f32x4){0.f, 0.f, 0.f, 0.f};

    int swz_s = ((lane >> 2) & 3) ^ ((lane >> 4) & 3);
    int gsel = ((lane & 3) ^ swz_s) * 8;
    const unsigned short* a0 = A  + (size_t)(bm + w * 16 + (lane >> 2)) * K + gsel;
    const unsigned short* b0 = Bt + (size_t)(bn + w * 16 + (lane >> 2)) * K + gsel;
    const unsigned short* b1 = b0 + (size_t)64 * K;
    unsigned short* lA0 = &As[(w * 16) * 32];
    unsigned short* lB0 = &Bs[(w * 16) * 32];
    unsigned short* lB1 = &Bs[(64 + w * 16) * 32];

    int swz_f = (l16 & 3) ^ ((l16 >> 2) & 3);
    int foff = (quad ^ swz_f) * 8;

    for (int k0 = 0; k0 < K; k0 += 32) {
        __syncthreads();
        gll16(a0 + k0, lA0);
        gll16(b0 + k0, lB0);
        gll16(b1 + k0, lB1);
        __syncthreads();
        bf16x8 af[2], bfr[4];
#pragma unroll
        for (int mi = 0; mi < 2; mi++)
            af[mi] = *(const bf16x8*)&As[(wrow * 32 + mi * 16 + l16) * 32 + foff];
#pragma unroll
        for (int ni = 0; ni < 4; ni++)
            bfr[ni] = *(const bf16x8*)&Bs[(wcol * 64 + ni * 16 + l16) * 32 + foff];
#pragma unroll
        for (int mi = 0; mi < 2; mi++)
#pragma unroll
            for (int ni = 0; ni < 4; ni++)
                acc[mi][ni] = __builtin_amdgcn_mfma_f32_16x16x32_bf16(af[mi], bfr[ni], acc[mi][ni], 0, 0, 0);
    }

#pragma unroll
    for (int mi = 0; mi < 2; mi++) {
#pragma unroll
        for (int r = 0; r < 4; r++) {
            int row = bm + wrow * 32 + mi * 16 + quad * 4 + r;
#pragma unroll
            for (int ni = 0; ni < 4; ni++) {
                int col = bn + wcol * 64 + ni * 16 + l16;
                float v = acc[mi][ni][r];
                if (act == 0) v += bias[col];
                else          v = v * sigmoidf_(v);
                C[(size_t)row * N + col] = v;
            }
        }
    }
}

// ---------------------------------------------------------------------------
// Kernel 2b: 32x64-tile GEMM for proj -> 768 blocks = exactly 3/CU (even
// tail). Wave w: 16x32 quadrant (wrow,wcol). A staged 8 rows/wave (32 active
// lanes, predicated gll16); B staged 16 rows/wave. Strip-relative XOR swizzle
// s(r) = (r&3)^((r>>2)&3). Per-output accumulation order identical to the
// previous 64x64 version (bitwise-identical C).
// ---------------------------------------------------------------------------
__global__ __launch_bounds__(256) void gemm64_kernel(const unsigned short* __restrict__ A,
                                                     const unsigned short* __restrict__ Bt,
                                                     const float* __restrict__ bias,
                                                     float* __restrict__ C,
                                                     int M, int N, int K) {
    __shared__ __align__(16) unsigned short As[32 * 32];
    __shared__ __align__(16) unsigned short Bs[64 * 32];
    int t = threadIdx.x;
    int lane = t & 63, w = t >> 6;
    int wrow = w >> 1, wcol = w & 1;
    int quad = lane >> 4, l16 = lane & 15;
    int bm = blockIdx.y * 32, bn = blockIdx.x * 64;

    f32x4 acc[2];
    acc[0] = (f32x4){0.f, 0.f, 0.f, 0.f};
    acc[1] = (f32x4){0.f, 0.f, 0.f, 0.f};

    // B staging: 16 rows/wave over 64 rows
    int rb = w * 16 + (lane >> 2);
    int sb = (rb & 3) ^ ((rb >> 2) & 3);
    int gsel_b = ((lane & 3) ^ sb) * 8;
    const unsigned short* b0 = Bt + (size_t)(bn + rb) * K + gsel_b;
    unsigned short* lB0 = &Bs[(w * 16) * 32];
    // A staging: 8 rows/wave over 32 rows; lanes < 32 active
    int ra = w * 8 + (lane >> 2);            // valid for lane < 32
    int sa2 = (ra & 3) ^ ((ra >> 2) & 3);
    int gsel_a = ((lane & 3) ^ sa2) * 8;
    const unsigned short* a0 = A + (size_t)(bm + (lane < 32 ? ra : 0)) * K + gsel_a;
    unsigned short* lA0 = &As[(w * 8) * 32];

    int swz_f = (l16 & 3) ^ ((l16 >> 2) & 3);
    int foff = (quad ^ swz_f) * 8;

    for (int k0 = 0; k0 < K; k0 += 32) {
        __syncthreads();
        if (lane < 32) gll16(a0 + k0, lA0);
        gll16(b0 + k0, lB0);
        __syncthreads();
        bf16x8 af = *(const bf16x8*)&As[(wrow * 16 + l16) * 32 + foff];
        bf16x8 bfr[2];
#pragma unroll
        for (int ni = 0; ni < 2; ni++)
            bfr[ni] = *(const bf16x8*)&Bs[(wcol * 32 + ni * 16 + l16) * 32 + foff];
#pragma unroll
        for (int ni = 0; ni < 2; ni++)
            acc[ni] = __builtin_amdgcn_mfma_f32_16x16x32_bf16(af, bfr[ni], acc[ni], 0, 0, 0);
    }

#pragma unroll
    for (int r = 0; r < 4; r++) {
        int row = bm + wrow * 16 + quad * 4 + r;
#pragma unroll
        for (int ni = 0; ni < 2; ni++) {
            int col = bn + wcol * 32 + ni * 16 + l16;
            C[(size_t)row * N + col] = acc[ni][r] + bias[col];
        }
    }
}

// ---------------------------------------------------------------------------
// Kernel 4 (pass A, split-fp16 MFMA + in-block gate)
// ---------------------------------------------------------------------------
__global__ __launch_bounds__(256) void passA_kernel(const float* __restrict__ qkv,
                                                    const float* __restrict__ h1,
                                                    const float* __restrict__ Wb2,
                                                    const float* __restrict__ temperature,
                                                    float* __restrict__ gate_out,
                                                    float* __restrict__ states) {
    int blk = blockIdx.x;
    int c = blk % NC, bh = blk / NC;
    int b = bh / HH, h = bh % HH;
    __shared__ __align__(16) unsigned short KTh[64 * SP], KTl[64 * SP];   // K^T[d][j]
    __shared__ __align__(16) unsigned short VTh[64 * SP], VTl[64 * SP];   // (V*w)^T[e][j]
    __shared__ float wsm[64];
    __shared__ float zpart[4][64];
    __shared__ float w2h[512];
    int t = threadIdx.x;
    size_t rowbase = (size_t)b * LL + c * CT;

    compute_gate_block<true>(t, h, rowbase, h1, Wb2, temperature, w2h, wsm, gate_out);

    {
        int d = t & 63, jg = t >> 6;
        const float* kbase = &qkv[(rowbase + jg * 16) * D3 + DD + h * DH + d];
        const float* vbase = kbase + DD;
        float zl = 0.f;
#pragma unroll
        for (int s = 0; s < 8; s++) {
            int j = jg * 16 + 2 * s;
            float k0 = elu1f_(kbase[(2 * s) * D3]);
            float k1 = elu1f_(kbase[(2 * s + 1) * D3]);
            zl += k0 + k1;
            unsigned short h0, l0, h1v, l1;
            splith(k0, h0, l0); splith(k1, h1v, l1);
            *(int*)&KTh[d * SP + j] = (int)h0 | ((int)h1v << 16);
            *(int*)&KTl[d * SP + j] = (int)l0 | ((int)l1 << 16);
            float v0 = vbase[(2 * s) * D3] * wsm[j];
            float v1 = vbase[(2 * s + 1) * D3] * wsm[j + 1];
            splith(v0, h0, l0); splith(v1, h1v, l1);
            *(int*)&VTh[d * SP + j] = (int)h0 | ((int)h1v << 16);
            *(int*)&VTl[d * SP + j] = (int)l0 | ((int)l1 << 16);
        }
        zpart[jg][d] = zl;
    }
    __syncthreads();
    int lane = t & 63, w = t >> 6;
    int q = lane >> 4, l16 = lane & 15;
    float* st = states + (size_t)(bh * NC + c) * 4160;
    int vrow = (w * 16 + l16) * SP;
    const f16x8 vh0 = *(const f16x8*)&VTh[vrow + q * 8];
    const f16x8 vh1 = *(const f16x8*)&VTh[vrow + 32 + q * 8];
    const f16x8 vl0 = *(const f16x8*)&VTl[vrow + q * 8];
    const f16x8 vl1 = *(const f16x8*)&VTl[vrow + 32 + q * 8];
#pragma unroll
    for (int dt = 0; dt < 4; dt++) {
        int krow = (dt * 16 + l16) * SP;
        const f16x8 kh0 = *(const f16x8*)&KTh[krow + q * 8];
        const f16x8 kh1 = *(const f16x8*)&KTh[krow + 32 + q * 8];
        const f16x8 kl0 = *(const f16x8*)&KTl[krow + q * 8];
        const f16x8 kl1 = *(const f16x8*)&KTl[krow + 32 + q * 8];
        f32x4 a = (f32x4){0.f, 0.f, 0.f, 0.f};
        a = __builtin_amdgcn_mfma_f32_16x16x32_f16(vh0, kl0, a, 0, 0, 0);
        a = __builtin_amdgcn_mfma_f32_16x16x32_f16(vh1, kl1, a, 0, 0, 0);
        a = __builtin_amdgcn_mfma_f32_16x16x32_f16(vl0, kh0, a, 0, 0, 0);
        a = __builtin_amdgcn_mfma_f32_16x16x32_f16(vl1, kh1, a, 0, 0, 0);
        a = __builtin_amdgcn_mfma_f32_16x16x32_f16(vh0, kh0, a, 0, 0, 0);
        a = __builtin_amdgcn_mfma_f32_16x16x32_f16(vh1, kh1, a, 0, 0, 0);
#pragma unroll
        for (int r = 0; r < 4; r++)
            st[(w * 16 + q * 4 + r) * 64 + dt * 16 + l16] = a[r];
    }
    if (t < 64) st[4096 + t] = zpart[0][t] + zpart[1][t] + zpart[2][t] + zpart[3][t];
}

// ---------------------------------------------------------------------------
// Kernel 5 (pass C, split-fp16 MFMA + in-block gate + head-LN fused)
// den2 computed from Q fragment registers (no LDS re-read).
// ---------------------------------------------------------------------------
__global__ __launch_bounds__(256) void passC_kernel(const float* __restrict__ qkv,
                                                    const float* __restrict__ h1,
                                                    const float* __restrict__ Wb2,
                                                    const float* __restrict__ temperature,
                                                    const float* __restrict__ states,
                                                    const float* __restrict__ mg,
                                                    const float* __restrict__ mb,
                                                    unsigned short* __restrict__ attn_bf) {
    int blk = blockIdx.x;
    int c = blk % NC, bh = blk / NC;
    int b = bh / HH, h = bh % HH;
    __shared__ __align__(16) unsigned short Qh[64 * SP], Ql[64 * SP];  // Q[i][d]
    __shared__ __align__(16) unsigned short Kh[64 * SP], Kl[64 * SP];  // K[j][d]
    __shared__ __align__(16) unsigned short VT[64 * SP];               // V^T[e][j]
    __shared__ __align__(16) unsigned short Sh[64 * SP], Sl[64 * SP];  // S_prev^T[e][d]
    __shared__ __align__(16) unsigned short At[64 * SP];               // Atilde[i][j]
    __shared__ float wsm[64], zb[64], den1[64], den2[64], mgs[64], mbs[64];
    __shared__ float w2h[512];
    int t = threadIdx.x;
    size_t rowbase = (size_t)b * LL + c * CT;

    compute_gate_block<false>(t, h, rowbase, h1, Wb2, temperature, w2h, wsm, nullptr);

    // ---- stage Q, K rows (elu, split fp16) ----
    {
        int j = t >> 2, f = t & 3;
        const float* qr = &qkv[(rowbase + j) * D3 + h * DH];
#pragma unroll
        for (int i2 = 0; i2 < 4; i2++) {
            int off = f * 16 + i2 * 4;
            float4 q4 = *(const float4*)&qr[off];
            ushort4 h4, l4;
            splith(elu1f_(q4.x), h4.x, l4.x); splith(elu1f_(q4.y), h4.y, l4.y);
            splith(elu1f_(q4.z), h4.z, l4.z); splith(elu1f_(q4.w), h4.w, l4.w);
            *(ushort4*)&Qh[j * SP + off] = h4;
            *(ushort4*)&Ql[j * SP + off] = l4;
            float4 k4 = *(const float4*)&qr[DD + off];
            splith(elu1f_(k4.x), h4.x, l4.x); splith(elu1f_(k4.y), h4.y, l4.y);
            splith(elu1f_(k4.z), h4.z, l4.z); splith(elu1f_(k4.w), h4.w, l4.w);
            *(ushort4*)&Kh[j * SP + off] = h4;
            *(ushort4*)&Kl[j * SP + off] = l4;
        }
    }
    // ---- stage V^T (fp16 hi only) ----
    {
        int e = t & 63, jg = t >> 6;
        const float* vbase = &qkv[(rowbase + jg * 16) * D3 + 2 * DD + h * DH + e];
#pragma unroll
        for (int s = 0; s < 8; s++) {
            int j = jg * 16 + 2 * s;
            float v0 = vbase[(2 * s) * D3];
            float v1 = vbase[(2 * s + 1) * D3];
            *(int*)&VT[e * SP + j] = packh2(v0, v1);
        }
    }
    // ---- stage S_prev^T = fp32 sum of chunk-local states -> split fp16 ----
    {
        int e = t >> 2, dbase = (t & 3) * 16;
        float acc[16];
#pragma unroll
        for (int i = 0; i < 16; i++) acc[i] = 0.f;
        for (int cp = 0; cp < c; cp++) {
            const float* st = states + (size_t)(bh * NC + cp) * 4160 + t * 16;
#pragma unroll
            for (int g2 = 0; g2 < 4; g2++) {
                float4 v4 = *(const float4*)&st[g2 * 4];
                acc[g2 * 4 + 0] += v4.x; acc[g2 * 4 + 1] += v4.y;
                acc[g2 * 4 + 2] += v4.z; acc[g2 * 4 + 3] += v4.w;
            }
        }
#pragma unroll
        for (int g2 = 0; g2 < 4; g2++) {
            ushort4 h4, l4;
            splith(acc[g2 * 4 + 0], h4.x, l4.x); splith(acc[g2 * 4 + 1], h4.y, l4.y);
            splith(acc[g2 * 4 + 2], h4.z, l4.z); splith(acc[g2 * 4 + 3], h4.w, l4.w);
            *(ushort4*)&Sh[e * SP + dbase + g2 * 4] = h4;
            *(ushort4*)&Sl[e * SP + dbase + g2 * 4] = l4;
        }
    }
    if (t < 64) {
        float z = 0.f;
        for (int cp = 0; cp < c; cp++)
            z += states[(size_t)(bh * NC + cp) * 4160 + 4096 + t];
        zb[t] = z;
        mgs[t] = mg[t];
        mbs[t] = mb[t];
    }
    __syncthreads();

    int lane = t & 63, w = t >> 6;
    int q = lane >> 4, l16 = lane & 15;
    int qrow = (w * 16 + l16) * SP;
    const f16x8 qh0 = *(const f16x8*)&Qh[qrow + q * 8];
    const f16x8 qh1 = *(const f16x8*)&Qh[qrow + 32 + q * 8];
    const f16x8 ql0 = *(const f16x8*)&Ql[qrow + q * 8];
    const f16x8 ql1 = *(const f16x8*)&Ql[qrow + 32 + q * 8];

    // ---- scores = Q K^T (3-term split) ----
    f32x4 sa[4];
#pragma unroll
    for (int jt = 0; jt < 4; jt++) {
        int krow = (jt * 16 + l16) * SP;
        const f16x8 kh0 = *(const f16x8*)&Kh[krow + q * 8];
        const f16x8 kh1 = *(const f16x8*)&Kh[krow + 32 + q * 8];
        const f16x8 kl0 = *(const f16x8*)&Kl[krow + q * 8];
        const f16x8 kl1 = *(const f16x8*)&Kl[krow + 32 + q * 8];
        f32x4 a = (f32x4){0.f, 0.f, 0.f, 0.f};
        a = __builtin_amdgcn_mfma_f32_16x16x32_f16(qh0, kl0, a, 0, 0, 0);
        a = __builtin_amdgcn_mfma_f32_16x16x32_f16(qh1, kl1, a, 0, 0, 0);
        a = __builtin_amdgcn_mfma_f32_16x16x32_f16(ql0, kh0, a, 0, 0, 0);
        a = __builtin_amdgcn_mfma_f32_16x16x32_f16(ql1, kh1, a, 0, 0, 0);
        a = __builtin_amdgcn_mfma_f32_16x16x32_f16(qh0, kh0, a, 0, 0, 0);
        a = __builtin_amdgcn_mfma_f32_16x16x32_f16(qh1, kh1, a, 0, 0, 0);
        sa[jt] = a;
    }
    // ---- causal mask, w-scale, At (fp16), fp32 den_intra ----
    float den_p[4] = {0.f, 0.f, 0.f, 0.f};
#pragma unroll
    for (int jt = 0; jt < 4; jt++) {
        int j = jt * 16 + l16;
        float wj = wsm[j];
#pragma unroll
        for (int r = 0; r < 4; r++) {
            int i = w * 16 + q * 4 + r;
            float a = (j <= i) ? sa[jt][r] : 0.f;
            den_p[r] += a;
            At[i * SP + j] = f2h(a * wj);
        }
    }
#pragma unroll
    for (int r = 0; r < 4; r++) {
        den_p[r] += __shfl_xor(den_p[r], 1);
        den_p[r] += __shfl_xor(den_p[r], 2);
        den_p[r] += __shfl_xor(den_p[r], 4);
        den_p[r] += __shfl_xor(den_p[r], 8);
    }
    if (l16 == 0) {
#pragma unroll
        for (int r = 0; r < 4; r++) den1[w * 16 + q * 4 + r] = den_p[r];
    }
    // ---- den_inter = Q . z_prev, from Q fragment registers (fp32) ----
    {
        float dp = 0.f;
#pragma unroll
        for (int s = 0; s < 8; s++) {
            dp += ((float)qh0[s] + (float)ql0[s]) * zb[q * 8 + s];
            dp += ((float)qh1[s] + (float)ql1[s]) * zb[32 + q * 8 + s];
        }
        dp += __shfl_xor(dp, 16);
        dp += __shfl_xor(dp, 32);
        if (q == 0) den2[w * 16 + l16] = dp;
    }
    __syncthreads();   // At / den1 / den2 visible

    // ---- num = Q S_prev^T (3-term) + At V^T ----
    const f16x8 af0 = *(const f16x8*)&At[qrow + q * 8];
    const f16x8 af1 = *(const f16x8*)&At[qrow + 32 + q * 8];
    f32x4 nacc[4];
#pragma unroll
    for (int et = 0; et < 4; et++) {
        int erow = (et * 16 + l16) * SP;
        const f16x8 sh0 = *(const f16x8*)&Sh[erow + q * 8];
        const f16x8 sh1 = *(const f16x8*)&Sh[erow + 32 + q * 8];
        const f16x8 sl0 = *(const f16x8*)&Sl[erow + q * 8];
        const f16x8 sl1 = *(const f16x8*)&Sl[erow + 32 + q * 8];
        const f16x8 vf0 = *(const f16x8*)&VT[erow + q * 8];
        const f16x8 vf1 = *(const f16x8*)&VT[erow + 32 + q * 8];
        f32x4 a = (f32x4){0.f, 0.f, 0.f, 0.f};
        a = __builtin_amdgcn_mfma_f32_16x16x32_f16(qh0, sl0, a, 0, 0, 0);
        a = __builtin_amdgcn_mfma_f32_16x16x32_f16(qh1, sl1, a, 0, 0, 0);
        a = __builtin_amdgcn_mfma_f32_16x16x32_f16(ql0, sh0, a, 0, 0, 0);
        a = __builtin_amdgcn_mfma_f32_16x16x32_f16(ql1, sh1, a, 0, 0, 0);
        a = __builtin_amdgcn_mfma_f32_16x16x32_f16(qh0, sh0, a, 0, 0, 0);
        a = __builtin_amdgcn_mfma_f32_16x16x32_f16(qh1, sh1, a, 0, 0, 0);
        a = __builtin_amdgcn_mfma_f32_16x16x32_f16(af0, vf0, a, 0, 0, 0);
        a = __builtin_amdgcn_mfma_f32_16x16x32_f16(af1, vf1, a, 0, 0, 0);
        nacc[et] = a;
    }
    // ---- out = num/den, head-LN, bf16 store ----
#pragma unroll
    for (int r = 0; r < 4; r++) {
        int i = w * 16 + q * 4 + r;
        float inv = 1.0f / (den1[i] + den2[i] + 1e-6f);
        float o[4];
        float s = 0.f, s2 = 0.f;
#pragma unroll
        for (int et = 0; et < 4; et++) {
            float v = nacc[et][r] * inv;
            o[et] = v;
            s += v;
            s2 += v * v;
        }
        s  += __shfl_xor(s, 1);  s  += __shfl_xor(s, 2);
        s  += __shfl_xor(s, 4);  s  += __shfl_xor(s, 8);
        s2 += __shfl_xor(s2, 1); s2 += __shfl_xor(s2, 2);
        s2 += __shfl_xor(s2, 4); s2 += __shfl_xor(s2, 8);
        float mu = s * (1.0f / DH);
        float var = s2 * (1.0f / DH) - mu * mu;
        float rstd = rsqrtf(var + 1e-5f);
        size_t gb = (rowbase + i) * DD + h * DH;
#pragma unroll
        for (int et = 0; et < 4; et++) {
            int e = et * 16 + l16;
            attn_bf[gb + e] = f2bf((o[et] - mu) * rstd * mgs[e] + mbs[e]);
        }
    }
}

// ---------------------------------------------------------------------------
extern "C" void kernel_launch(void* const* d_in, const int* in_sizes, int n_in,
                              void* d_out, int out_size, void* d_ws, size_t ws_size,
                              hipStream_t stream) {
    const float* x    = (const float*)d_in[0];
    const float* Wqkv = (const float*)d_in[1];
    const float* bqkv = (const float*)d_in[2];
    const float* Wb1  = (const float*)d_in[3];
    const float* Wb2  = (const float*)d_in[4];
    const float* temperature = (const float*)d_in[5];
    const float* Wproj = (const float*)d_in[6];
    const float* bproj = (const float*)d_in[7];
    const float* ln_g = (const float*)d_in[8];
    const float* ln_b = (const float*)d_in[9];
    const float* mn_g = (const float*)d_in[10];
    const float* mn_b = (const float*)d_in[11];

    float* out0     = (float*)d_out;                    // (B,L,D)
    float* gate_out = out0 + (size_t)BL * DD;           // (B,L,H)

    float* ws = (float*)d_ws;
    float* qkv    = ws;                                   // 4,718,592 f32
    float* h1     = qkv + (size_t)BL * D3;                //   262,144
    float* states = h1 + (size_t)BL * RR;                 // 1,597,440
    unsigned short* xnbf  = (unsigned short*)(states + (size_t)BB * HH * NC * 4160);
    unsigned short* xbf    = xnbf + (size_t)BL * DD;
    unsigned short* attnbf = xbf + (size_t)BL * DD;
    unsigned short* wqkvt  = attnbf + (size_t)BL * DD;
    unsigned short* wb1t   = wqkvt + (size_t)D3 * DD;
    unsigned short* wprojt = wb1t + (size_t)DD * RR;

    // 1. LN + x->bf16 + all weight transposes
    prep_kernel<<<4448, 256, 0, stream>>>(x, ln_g, ln_b, xnbf, xbf,
                                          Wqkv, Wb1, Wproj, wqkvt, wb1t, wprojt);
    // 2. qkv GEMM + Wb1 GEMM fused (64x128 tiles, 608 blocks)
    gemm_big_kernel<<<608, 256, 0, stream>>>(xnbf, wqkvt, bqkv, qkv, xbf, wb1t, h1);
    // 3. chunk-local states (split-fp16 MFMA + in-block gate, 384 blocks)
    passA_kernel<<<BB * HH * NC, 256, 0, stream>>>(qkv, h1, Wb2, temperature, gate_out, states);
    // 4. replay (split-fp16 MFMA + in-block gate) + inline prefix + head-LN -> bf16
    passC_kernel<<<BB * HH * NC, 256, 0, stream>>>(qkv, h1, Wb2, temperature, states, mn_g, mn_b, attnbf);
    // 5. out = attn @ Wproj + bproj (32x64 tiles -> 768 blocks, 3/CU even)
    gemm64_kernel<<<dim3(DD / 64, BL / 32), 256, 0, stream>>>(attnbf, wprojt, bproj, out0, BL, DD, DD);
}